// Round 1
// baseline (1193.927 us; speedup 1.0000x reference)
//
#include <hip/hip_runtime.h>

#define NNODES 100000
#define NEDGES 1600000

__device__ __forceinline__ unsigned short f2bf(float f) {
  unsigned int u = __float_as_uint(f);
  u = (u + 0x7FFFu + ((u >> 16) & 1u)) >> 16;
  return (unsigned short)u;
}
__device__ __forceinline__ float bf2f(unsigned short h) {
  return __uint_as_float(((unsigned int)h) << 16);
}

// ---------------- CSR build (bucket by dst) ----------------
__global__ void count_kernel(const int* __restrict__ dst, int* __restrict__ cnt) {
  int e = blockIdx.x * 256 + threadIdx.x;
  if (e < NEDGES) atomicAdd(&cnt[dst[e]], 1);
}

__global__ void alloc_kernel(const int* __restrict__ cnt, int* __restrict__ startA,
                             int* __restrict__ cursor, float* __restrict__ dis,
                             int* __restrict__ total) {
  int v = blockIdx.x * 256 + threadIdx.x;
  if (v < NNODES) {
    int c = cnt[v];
    int s = atomicAdd(total, c);
    startA[v] = s;
    cursor[v] = s;
    dis[v] = rsqrtf((float)(c + 1));  // deg = indeg + self loop
  }
}

__global__ void fill_kernel(const int* __restrict__ src, const int* __restrict__ dst,
                            int* __restrict__ cursor, int* __restrict__ csr) {
  int e = blockIdx.x * 256 + threadIdx.x;
  if (e < NEDGES) {
    int pos = atomicAdd(&cursor[dst[e]], 1);
    csr[pos] = src[e];
  }
}

// ---------------- tall-skinny GEMM: out[r,:] = X[r,:K] @ W[K,HOUT] ----------------
// optional row scale by dis[r] (pre-aggregation) and col bias add; optional bf16 out.
// 64 rows/block, 256 threads = 16 col-threads x 16 row-threads, 4 rows x HOUT/16 cols per thread.
template <int K, int HOUT, bool SCALE, bool BIAS, bool BF16OUT>
__global__ __launch_bounds__(256)
void gemm_kernel(const float* __restrict__ X, const float* __restrict__ W,
                 const float* __restrict__ dis, const float* __restrict__ bias,
                 void* __restrict__ outv) {
  constexpr int TN = HOUT / 16;
  constexpr int NF4 = TN / 4;
  __shared__ float Ws[32 * HOUT];     // K-chunked weight tile
  __shared__ float Xs[64][K + 4];     // +4 pad: rows 4 banks apart
  const int tid = threadIdx.x;
  const int ct = tid & 15;
  const int rt = tid >> 4;
  const int rowBase = blockIdx.x * 64;

  // stage X tile (64 x K); clamp OOB rows (last block) to row N-1, stores guarded later
  constexpr int XF4 = 64 * K / 4 / 256;
#pragma unroll
  for (int i = 0; i < XF4; ++i) {
    int idx = tid + i * 256;
    int r = idx / (K / 4);
    int c = idx - r * (K / 4);
    int rg = rowBase + r;
    if (rg >= NNODES) rg = NNODES - 1;
    float4 v = *(const float4*)&X[(size_t)rg * K + c * 4];
    *(float4*)&Xs[r][c * 4] = v;
  }

  float4 acc[4][NF4] = {};

  constexpr int WF4 = 32 * HOUT / 4 / 256;
  for (int kc = 0; kc < K; kc += 32) {
    __syncthreads();
#pragma unroll
    for (int i = 0; i < WF4; ++i) {
      int idx = tid + i * 256;
      ((float4*)Ws)[idx] = *(const float4*)&W[(size_t)kc * HOUT + idx * 4];
    }
    __syncthreads();
#pragma unroll
    for (int k2 = 0; k2 < 32; ++k2) {
      float xv[4];
#pragma unroll
      for (int t = 0; t < 4; ++t) xv[t] = Xs[rt * 4 + t][kc + k2];
#pragma unroll
      for (int i = 0; i < NF4; ++i) {
        float4 w = *(const float4*)&Ws[k2 * HOUT + ct * TN + i * 4];
#pragma unroll
        for (int t = 0; t < 4; ++t) {
          acc[t][i].x = fmaf(xv[t], w.x, acc[t][i].x);
          acc[t][i].y = fmaf(xv[t], w.y, acc[t][i].y);
          acc[t][i].z = fmaf(xv[t], w.z, acc[t][i].z);
          acc[t][i].w = fmaf(xv[t], w.w, acc[t][i].w);
        }
      }
    }
  }

#pragma unroll
  for (int t = 0; t < 4; ++t) {
    int row = rowBase + rt * 4 + t;
    if (row >= NNODES) continue;
    float s = SCALE ? dis[row] : 1.0f;
#pragma unroll
    for (int i = 0; i < NF4; ++i) {
      int col = ct * TN + i * 4;
      float4 a = acc[t][i];
      a.x *= s; a.y *= s; a.z *= s; a.w *= s;
      if (BIAS) {
        float4 b = *(const float4*)&bias[col];
        a.x += b.x; a.y += b.y; a.z += b.z; a.w += b.w;
      }
      if (BF16OUT) {
        ushort4 u;
        u.x = f2bf(a.x); u.y = f2bf(a.y); u.z = f2bf(a.z); u.w = f2bf(a.w);
        *(ushort4*)&((unsigned short*)outv)[(size_t)row * HOUT + col] = u;
      } else {
        *(float4*)&((float*)outv)[(size_t)row * HOUT + col] = a;
      }
    }
  }
}

// ---------------- aggregation: one wave per node ----------------
// out[v] = relu(dis[v] * (hws[v] + sum_{u in csr bucket} hws[u]) + bias)
template <int HOUT>
__global__ __launch_bounds__(256)
void agg_kernel(const float* __restrict__ hws, const int* __restrict__ csr,
                const int* __restrict__ startA, const int* __restrict__ cnt,
                const float* __restrict__ dis, const float* __restrict__ bias,
                float* __restrict__ out) {
  int gid = blockIdx.x * 256 + threadIdx.x;
  int v = gid >> 6;
  int lane = gid & 63;
  if (v >= NNODES) return;
  constexpr int PER = HOUT / 64;
  float acc[PER];
  if constexpr (PER == 2) {
    float2 o = *(const float2*)&hws[(size_t)v * HOUT + lane * 2];
    acc[0] = o.x; acc[1] = o.y;
  } else {
    acc[0] = hws[(size_t)v * HOUT + lane];
  }
  int s0 = startA[v], c = cnt[v];
  for (int base = 0; base < c; base += 64) {
    int rem = c - base;
    int idx = 0;
    if (lane < rem) idx = csr[s0 + base + lane];
    int m = rem < 64 ? rem : 64;
    for (int j = 0; j < m; ++j) {
      int u = __shfl(idx, j);
      if constexpr (PER == 2) {
        float2 r = *(const float2*)&hws[(size_t)u * HOUT + lane * 2];
        acc[0] += r.x; acc[1] += r.y;
      } else {
        acc[0] += hws[(size_t)u * HOUT + lane];
      }
    }
  }
  float d = dis[v];
#pragma unroll
  for (int i = 0; i < PER; ++i) {
    float r = fmaf(d, acc[i], bias[lane * PER + i]);
    out[(size_t)v * HOUT + lane * PER + i] = r > 0.0f ? r : 0.0f;
  }
}

// ---------------- edge classifier: one wave per edge ----------------
// out[e] = sigmoid( sum_j relu(A[src][j] + B[dst][j]) * lw2[j] + lb2 )
// (lb1 already folded into A)
__global__ __launch_bounds__(256)
void edge_kernel(const unsigned short* __restrict__ A, const unsigned short* __restrict__ B,
                 const int* __restrict__ src, const int* __restrict__ dst,
                 const float* __restrict__ lw2, const float* __restrict__ lb2,
                 float* __restrict__ out) {
  int gid = blockIdx.x * 256 + threadIdx.x;
  int e = gid >> 6;
  int lane = gid & 63;
  if (e >= NEDGES) return;
  int s = src[e], d = dst[e];
  ushort4 av = *(const ushort4*)&A[(size_t)s * 256 + lane * 4];
  ushort4 bv = *(const ushort4*)&B[(size_t)d * 256 + lane * 4];
  float4 w = *(const float4*)&lw2[lane * 4];
  float h0 = bf2f(av.x) + bf2f(bv.x);
  float h1 = bf2f(av.y) + bf2f(bv.y);
  float h2 = bf2f(av.z) + bf2f(bv.z);
  float h3 = bf2f(av.w) + bf2f(bv.w);
  h0 = h0 > 0.0f ? h0 : 0.0f;
  h1 = h1 > 0.0f ? h1 : 0.0f;
  h2 = h2 > 0.0f ? h2 : 0.0f;
  h3 = h3 > 0.0f ? h3 : 0.0f;
  float acc = h0 * w.x + h1 * w.y + h2 * w.z + h3 * w.w;
#pragma unroll
  for (int off = 32; off; off >>= 1) acc += __shfl_xor(acc, off);
  if (lane == 0) out[e] = 1.0f / (1.0f + expf(-(acc + lb2[0])));
}

extern "C" void kernel_launch(void* const* d_in, const int* in_sizes, int n_in,
                              void* d_out, int out_size, void* d_ws, size_t ws_size,
                              hipStream_t stream) {
  const float* x   = (const float*)d_in[0];
  const int*   ei  = (const int*)d_in[1];
  const float* W0  = (const float*)d_in[2];
  const float* b0  = (const float*)d_in[3];
  const float* W1  = (const float*)d_in[4];
  const float* b1  = (const float*)d_in[5];
  const float* W2  = (const float*)d_in[6];
  const float* b2  = (const float*)d_in[7];
  const float* lw1 = (const float*)d_in[8];
  const float* lb1 = (const float*)d_in[9];
  const float* lw2 = (const float*)d_in[10];
  const float* lb2 = (const float*)d_in[11];
  float* out = (float*)d_out;
  const int* src = ei;
  const int* dst = ei + NEDGES;

  char* ws = (char*)d_ws;
  size_t off = 0;
  auto alloc = [&](size_t bytes) -> void* {
    void* p = ws + off;
    off += (bytes + 255) & ~(size_t)255;
    return p;
  };
  int*   cnt    = (int*)alloc((size_t)NNODES * 4);
  int*   startA = (int*)alloc((size_t)NNODES * 4);
  int*   cursor = (int*)alloc((size_t)NNODES * 4);
  float* dis    = (float*)alloc((size_t)NNODES * 4);
  int*   total  = (int*)alloc(256);
  int*   csr    = (int*)alloc((size_t)NEDGES * 4);
  float* P      = (float*)alloc((size_t)NNODES * 128 * 4);   // hws buffer
  float* Q      = (float*)alloc((size_t)NNODES * 128 * 4);   // z buffer
  unsigned short* Abuf = (unsigned short*)alloc((size_t)NNODES * 256 * 2);
  unsigned short* Bbuf = (unsigned short*)alloc((size_t)NNODES * 256 * 2);
  // total ws use: ~213 MB

  hipMemsetAsync(cnt, 0, (size_t)NNODES * 4, stream);
  hipMemsetAsync(total, 0, 4, stream);
  count_kernel<<<(NEDGES + 255) / 256, 256, 0, stream>>>(dst, cnt);
  alloc_kernel<<<(NNODES + 255) / 256, 256, 0, stream>>>(cnt, startA, cursor, dis, total);
  fill_kernel<<<(NEDGES + 255) / 256, 256, 0, stream>>>(src, dst, cursor, csr);

  const int GB = (NNODES + 63) / 64;  // 1563 blocks for gemm
  const int AB = (NNODES * 64) / 256; // 25000 blocks for agg (exact)

  // layer 0: hws0 = (x@W0)*dis ; z1 = relu(dis*(agg)+b0)
  gemm_kernel<128, 128, true, false, false><<<GB, 256, 0, stream>>>(x, W0, dis, nullptr, P);
  agg_kernel<128><<<AB, 256, 0, stream>>>(P, csr, startA, cnt, dis, b0, Q);
  // layer 1
  gemm_kernel<128, 128, true, false, false><<<GB, 256, 0, stream>>>(Q, W1, dis, nullptr, P);
  agg_kernel<128><<<AB, 256, 0, stream>>>(P, csr, startA, cnt, dis, b1, Q);
  // layer 2 (EMB=64)
  gemm_kernel<128, 64, true, false, false><<<GB, 256, 0, stream>>>(Q, W2, dis, nullptr, P);
  agg_kernel<64><<<AB, 256, 0, stream>>>(P, csr, startA, cnt, dis, b2, Q);

  // edge MLP split: A = z@lw1[0:64,:] + lb1 ; B = z@lw1[64:128,:]
  gemm_kernel<64, 256, false, true, true><<<GB, 256, 0, stream>>>(Q, lw1, nullptr, lb1, Abuf);
  gemm_kernel<64, 256, false, false, true><<<GB, 256, 0, stream>>>(Q, lw1 + 64 * 256, nullptr, nullptr, Bbuf);

  // per-edge: gather A[src], B[dst], relu-dot with lw2, sigmoid
  edge_kernel<<<((size_t)NEDGES * 64) / 256, 256, 0, stream>>>(Abuf, Bbuf, src, dst, lw2, lb2, out);
}

// Round 3
// 1177.658 us; speedup vs baseline: 1.0138x; 1.0138x over previous
//
#include <hip/hip_runtime.h>

#define NNODES 100000
#define NEDGES 1600000

__device__ __forceinline__ unsigned short f2bf(float f) {
  unsigned int u = __float_as_uint(f);
  u = (u + 0x7FFFu + ((u >> 16) & 1u)) >> 16;
  return (unsigned short)u;
}
__device__ __forceinline__ float bf2f(unsigned short h) {
  return __uint_as_float(((unsigned int)h) << 16);
}

// ---------------- CSR build: count both sides in one pass ----------------
__global__ void count_both_kernel(const int* __restrict__ src, const int* __restrict__ dst,
                                  int* __restrict__ cntD, int* __restrict__ cntS) {
  int e = blockIdx.x * 256 + threadIdx.x;
  if (e < NEDGES) {
    atomicAdd(&cntD[dst[e]], 1);
    atomicAdd(&cntS[src[e]], 1);
  }
}

__global__ void alloc_kernel(const int* __restrict__ cntD, int* __restrict__ startD,
                             int* __restrict__ curD, float* __restrict__ dis,
                             int* __restrict__ totD,
                             const int* __restrict__ cntS, int* __restrict__ startS,
                             int* __restrict__ curS, int* __restrict__ totS) {
  int v = blockIdx.x * 256 + threadIdx.x;
  if (v < NNODES) {
    int c = cntD[v];
    int s = atomicAdd(totD, c);
    startD[v] = s;
    curD[v] = s;
    dis[v] = rsqrtf((float)(c + 1));  // deg = indeg + self loop
    int c2 = cntS[v];
    int s2 = atomicAdd(totS, c2);
    startS[v] = s2;
    curS[v] = s2;
  }
}

__global__ void fill_both_kernel(const int* __restrict__ src, const int* __restrict__ dst,
                                 int* __restrict__ curD, int* __restrict__ csrD,
                                 int* __restrict__ curS, int* __restrict__ csrSdst,
                                 int* __restrict__ csrSeid) {
  int e = blockIdx.x * 256 + threadIdx.x;
  if (e < NEDGES) {
    int s = src[e], d = dst[e];
    int pd = atomicAdd(&curD[d], 1);
    csrD[pd] = s;
    int ps = atomicAdd(&curS[s], 1);
    csrSdst[ps] = d;
    csrSeid[ps] = e;
  }
}

// ---------------- tall-skinny GEMM: out[r,:] = X[r,:K] @ W[K,HOUT] ----------------
template <int K, int HOUT, bool SCALE, bool BIAS, bool BF16OUT>
__global__ __launch_bounds__(256)
void gemm_kernel(const float* __restrict__ X, const float* __restrict__ W,
                 const float* __restrict__ dis, const float* __restrict__ bias,
                 void* __restrict__ outv) {
  constexpr int TN = HOUT / 16;
  constexpr int NF4 = TN / 4;
  __shared__ float Ws[32 * HOUT];
  __shared__ float Xs[64][K + 4];
  const int tid = threadIdx.x;
  const int ct = tid & 15;
  const int rt = tid >> 4;
  const int rowBase = blockIdx.x * 64;

  constexpr int XF4 = 64 * K / 4 / 256;
#pragma unroll
  for (int i = 0; i < XF4; ++i) {
    int idx = tid + i * 256;
    int r = idx / (K / 4);
    int c = idx - r * (K / 4);
    int rg = rowBase + r;
    if (rg >= NNODES) rg = NNODES - 1;
    float4 v = *(const float4*)&X[(size_t)rg * K + c * 4];
    *(float4*)&Xs[r][c * 4] = v;
  }

  float4 acc[4][NF4] = {};

  constexpr int WF4 = 32 * HOUT / 4 / 256;
  for (int kc = 0; kc < K; kc += 32) {
    __syncthreads();
#pragma unroll
    for (int i = 0; i < WF4; ++i) {
      int idx = tid + i * 256;
      ((float4*)Ws)[idx] = *(const float4*)&W[(size_t)kc * HOUT + idx * 4];
    }
    __syncthreads();
#pragma unroll
    for (int k2 = 0; k2 < 32; ++k2) {
      float xv[4];
#pragma unroll
      for (int t = 0; t < 4; ++t) xv[t] = Xs[rt * 4 + t][kc + k2];
#pragma unroll
      for (int i = 0; i < NF4; ++i) {
        float4 w = *(const float4*)&Ws[k2 * HOUT + ct * TN + i * 4];
#pragma unroll
        for (int t = 0; t < 4; ++t) {
          acc[t][i].x = fmaf(xv[t], w.x, acc[t][i].x);
          acc[t][i].y = fmaf(xv[t], w.y, acc[t][i].y);
          acc[t][i].z = fmaf(xv[t], w.z, acc[t][i].z);
          acc[t][i].w = fmaf(xv[t], w.w, acc[t][i].w);
        }
      }
    }
  }

#pragma unroll
  for (int t = 0; t < 4; ++t) {
    int row = rowBase + rt * 4 + t;
    if (row >= NNODES) continue;
    float s = SCALE ? dis[row] : 1.0f;
#pragma unroll
    for (int i = 0; i < NF4; ++i) {
      int col = ct * TN + i * 4;
      float4 a = acc[t][i];
      a.x *= s; a.y *= s; a.z *= s; a.w *= s;
      if (BIAS) {
        float4 b = *(const float4*)&bias[col];
        a.x += b.x; a.y += b.y; a.z += b.z; a.w += b.w;
      }
      if (BF16OUT) {
        ushort4 u;
        u.x = f2bf(a.x); u.y = f2bf(a.y); u.z = f2bf(a.z); u.w = f2bf(a.w);
        *(ushort4*)&((unsigned short*)outv)[(size_t)row * HOUT + col] = u;
      } else {
        *(float4*)&((float*)outv)[(size_t)row * HOUT + col] = a;
      }
    }
  }
}

// ---------------- aggregation: one wave per node, 4-deep gather pipeline ----------------
template <int HOUT>
__global__ __launch_bounds__(256)
void agg_kernel(const float* __restrict__ hws, const int* __restrict__ csr,
                const int* __restrict__ startA, const int* __restrict__ cnt,
                const float* __restrict__ dis, const float* __restrict__ bias,
                float* __restrict__ out) {
  int gid = blockIdx.x * 256 + threadIdx.x;
  int v = gid >> 6;
  int lane = gid & 63;
  constexpr int PER = HOUT / 64;
  float acc[PER];
  if constexpr (PER == 2) {
    float2 o = *(const float2*)&hws[(size_t)v * HOUT + lane * 2];
    acc[0] = o.x; acc[1] = o.y;
  } else {
    acc[0] = hws[(size_t)v * HOUT + lane];
  }
  int s0 = startA[v], c = cnt[v];
  for (int base = 0; base < c; base += 64) {
    int rem = c - base;
    int m = rem < 64 ? rem : 64;
    int idx = 0;
    if (lane < m) idx = csr[s0 + base + lane];
    int j = 0;
    for (; j + 4 <= m; j += 4) {
      int u0 = __shfl(idx, j);
      int u1 = __shfl(idx, j + 1);
      int u2 = __shfl(idx, j + 2);
      int u3 = __shfl(idx, j + 3);
      if constexpr (PER == 2) {
        float2 r0 = *(const float2*)&hws[(size_t)u0 * HOUT + lane * 2];
        float2 r1 = *(const float2*)&hws[(size_t)u1 * HOUT + lane * 2];
        float2 r2 = *(const float2*)&hws[(size_t)u2 * HOUT + lane * 2];
        float2 r3 = *(const float2*)&hws[(size_t)u3 * HOUT + lane * 2];
        acc[0] += r0.x + r1.x + r2.x + r3.x;
        acc[1] += r0.y + r1.y + r2.y + r3.y;
      } else {
        float r0 = hws[(size_t)u0 * HOUT + lane];
        float r1 = hws[(size_t)u1 * HOUT + lane];
        float r2 = hws[(size_t)u2 * HOUT + lane];
        float r3 = hws[(size_t)u3 * HOUT + lane];
        acc[0] += (r0 + r1) + (r2 + r3);
      }
    }
    for (; j < m; ++j) {
      int u = __shfl(idx, j);
      if constexpr (PER == 2) {
        float2 r = *(const float2*)&hws[(size_t)u * HOUT + lane * 2];
        acc[0] += r.x; acc[1] += r.y;
      } else {
        acc[0] += hws[(size_t)u * HOUT + lane];
      }
    }
  }
  float d = dis[v];
#pragma unroll
  for (int i = 0; i < PER; ++i) {
    float r = fmaf(d, acc[i], bias[lane * PER + i]);
    out[(size_t)v * HOUT + lane * PER + i] = r > 0.0f ? r : 0.0f;
  }
}

// ---------------- edge classifier: one wave per SRC node ----------------
__global__ __launch_bounds__(256)
void edge_kernel(const unsigned short* __restrict__ A, const unsigned short* __restrict__ B,
                 const int* __restrict__ csrSdst, const int* __restrict__ csrSeid,
                 const int* __restrict__ startS, const int* __restrict__ cntS,
                 const float* __restrict__ lw2, const float* __restrict__ lb2,
                 float* __restrict__ out) {
  int gid = blockIdx.x * 256 + threadIdx.x;
  int v = gid >> 6;
  int lane = gid & 63;
  ushort4 av = *(const ushort4*)&A[(size_t)v * 256 + lane * 4];
  float a0 = bf2f(av.x), a1 = bf2f(av.y), a2 = bf2f(av.z), a3 = bf2f(av.w);
  float4 w = *(const float4*)&lw2[lane * 4];
  float lb = lb2[0];
  int s0 = startS[v], c = cntS[v];
  for (int base = 0; base < c; base += 64) {
    int rem = c - base;
    int m = rem < 64 ? rem : 64;
    int dj = 0, ej = 0;
    if (lane < m) {
      dj = csrSdst[s0 + base + lane];
      ej = csrSeid[s0 + base + lane];
    }
    for (int j = 0; j < m; j += 2) {
      bool two = (j + 1 < m);
      int d0 = __shfl(dj, j);
      int e0 = __shfl(ej, j);
      int d1 = __shfl(dj, (j + 1) & 63);
      int e1 = __shfl(ej, (j + 1) & 63);
      ushort4 b0 = *(const ushort4*)&B[(size_t)d0 * 256 + lane * 4];
      ushort4 b1 = *(const ushort4*)&B[(size_t)d1 * 256 + lane * 4];
      float h00 = a0 + bf2f(b0.x), h01 = a1 + bf2f(b0.y), h02 = a2 + bf2f(b0.z), h03 = a3 + bf2f(b0.w);
      float h10 = a0 + bf2f(b1.x), h11 = a1 + bf2f(b1.y), h12 = a2 + bf2f(b1.z), h13 = a3 + bf2f(b1.w);
      h00 = h00 > 0.0f ? h00 : 0.0f; h01 = h01 > 0.0f ? h01 : 0.0f;
      h02 = h02 > 0.0f ? h02 : 0.0f; h03 = h03 > 0.0f ? h03 : 0.0f;
      h10 = h10 > 0.0f ? h10 : 0.0f; h11 = h11 > 0.0f ? h11 : 0.0f;
      h12 = h12 > 0.0f ? h12 : 0.0f; h13 = h13 > 0.0f ? h13 : 0.0f;
      float acc0 = fmaf(h03, w.w, fmaf(h02, w.z, fmaf(h01, w.y, h00 * w.x)));
      float acc1 = fmaf(h13, w.w, fmaf(h12, w.z, fmaf(h11, w.y, h10 * w.x)));
#pragma unroll
      for (int off = 32; off; off >>= 1) {
        acc0 += __shfl_xor(acc0, off);
        acc1 += __shfl_xor(acc1, off);
      }
      if (lane == 0) {
        out[e0] = 1.0f / (1.0f + expf(-(acc0 + lb)));
        if (two) out[e1] = 1.0f / (1.0f + expf(-(acc1 + lb)));
      }
    }
  }
}

extern "C" void kernel_launch(void* const* d_in, const int* in_sizes, int n_in,
                              void* d_out, int out_size, void* d_ws, size_t ws_size,
                              hipStream_t stream) {
  const float* x   = (const float*)d_in[0];
  const int*   ei  = (const int*)d_in[1];
  const float* W0  = (const float*)d_in[2];
  const float* b0  = (const float*)d_in[3];
  const float* W1  = (const float*)d_in[4];
  const float* b1  = (const float*)d_in[5];
  const float* W2  = (const float*)d_in[6];
  const float* b2  = (const float*)d_in[7];
  const float* lw1 = (const float*)d_in[8];
  const float* lb1 = (const float*)d_in[9];
  const float* lw2 = (const float*)d_in[10];
  const float* lb2 = (const float*)d_in[11];
  float* out = (float*)d_out;
  const int* src = ei;
  const int* dst = ei + NEDGES;

  char* ws = (char*)d_ws;
  size_t off = 0;
  auto alloc = [&](size_t bytes) -> void* {
    void* p = ws + off;
    off += (bytes + 255) & ~(size_t)255;
    return p;
  };
  // cnt block allocated as ONE contiguous region so a single memset covers it
  // exactly (NNODES*4 is NOT 256-aligned — separate allocs left a poison gap, R2 crash).
  int*   cntD   = (int*)alloc((size_t)NNODES * 8);   // [cntD | cntS]
  int*   cntS   = cntD + NNODES;
  int*   startD = (int*)alloc((size_t)NNODES * 4);
  int*   startS = (int*)alloc((size_t)NNODES * 4);
  int*   curD   = (int*)alloc((size_t)NNODES * 4);
  int*   curS   = (int*)alloc((size_t)NNODES * 4);
  float* dis    = (float*)alloc((size_t)NNODES * 4);
  int*   totD   = (int*)alloc(512);                  // [totD | totS] in one 512B block
  int*   totS   = totD + 64;
  int*   csrD   = (int*)alloc((size_t)NEDGES * 4);
  int*   csrSdst= (int*)alloc((size_t)NEDGES * 4);
  int*   csrSeid= (int*)alloc((size_t)NEDGES * 4);
  float* P      = (float*)alloc((size_t)NNODES * 128 * 4);
  float* Q      = (float*)alloc((size_t)NNODES * 128 * 4);
  unsigned short* Abuf = (unsigned short*)alloc((size_t)NNODES * 256 * 2);
  unsigned short* Bbuf = (unsigned short*)alloc((size_t)NNODES * 256 * 2);

  hipMemsetAsync(cntD, 0, (size_t)NNODES * 8, stream);
  hipMemsetAsync(totD, 0, 512, stream);
  count_both_kernel<<<(NEDGES + 255) / 256, 256, 0, stream>>>(src, dst, cntD, cntS);
  alloc_kernel<<<(NNODES + 255) / 256, 256, 0, stream>>>(cntD, startD, curD, dis, totD,
                                                         cntS, startS, curS, totS);
  fill_both_kernel<<<(NEDGES + 255) / 256, 256, 0, stream>>>(src, dst, curD, csrD,
                                                             curS, csrSdst, csrSeid);

  const int GB = (NNODES + 63) / 64;   // gemm blocks
  const int AB = (NNODES * 64) / 256;  // one wave per node (exact: 25000)

  gemm_kernel<128, 128, true, false, false><<<GB, 256, 0, stream>>>(x, W0, dis, nullptr, P);
  agg_kernel<128><<<AB, 256, 0, stream>>>(P, csrD, startD, cntD, dis, b0, Q);
  gemm_kernel<128, 128, true, false, false><<<GB, 256, 0, stream>>>(Q, W1, dis, nullptr, P);
  agg_kernel<128><<<AB, 256, 0, stream>>>(P, csrD, startD, cntD, dis, b1, Q);
  gemm_kernel<128, 64, true, false, false><<<GB, 256, 0, stream>>>(Q, W2, dis, nullptr, P);
  agg_kernel<64><<<AB, 256, 0, stream>>>(P, csrD, startD, cntD, dis, b2, Q);

  gemm_kernel<64, 256, false, true, true><<<GB, 256, 0, stream>>>(Q, lw1, nullptr, lb1, Abuf);
  gemm_kernel<64, 256, false, false, true><<<GB, 256, 0, stream>>>(Q, lw1 + 64 * 256, nullptr, nullptr, Bbuf);

  edge_kernel<<<AB, 256, 0, stream>>>(Abuf, Bbuf, csrSdst, csrSeid, startS, cntS, lw2, lb2, out);
}

// Round 4
// 954.672 us; speedup vs baseline: 1.2506x; 1.2336x over previous
//
#include <hip/hip_runtime.h>

#define NNODES 100000
#define NEDGES 1600000

__device__ __forceinline__ unsigned short f2bf(float f) {
  unsigned int u = __float_as_uint(f);
  u = (u + 0x7FFFu + ((u >> 16) & 1u)) >> 16;
  return (unsigned short)u;
}
__device__ __forceinline__ float bf2f(unsigned short h) {
  return __uint_as_float(((unsigned int)h) << 16);
}

// ---------------- CSR build (dst side only) ----------------
__global__ void count_kernel(const int* __restrict__ dst, int* __restrict__ cntD) {
  int e = blockIdx.x * 256 + threadIdx.x;
  if (e < NEDGES) atomicAdd(&cntD[dst[e]], 1);
}

__global__ void alloc_kernel(const int* __restrict__ cntD, int* __restrict__ startD,
                             int* __restrict__ curD, float* __restrict__ dis,
                             int* __restrict__ totD) {
  int v = blockIdx.x * 256 + threadIdx.x;
  if (v < NNODES) {
    int c = cntD[v];
    int s = atomicAdd(totD, c);
    startD[v] = s;
    curD[v] = s;
    dis[v] = rsqrtf((float)(c + 1));  // deg = in-degree + self loop
  }
}

// one 8B scattered store per edge: (src, eid) packed
__global__ void fill_kernel(const int* __restrict__ src, const int* __restrict__ dst,
                            int* __restrict__ curD, int2* __restrict__ csrPair) {
  int e = blockIdx.x * 256 + threadIdx.x;
  if (e < NEDGES) {
    int s = src[e], d = dst[e];
    int pd = atomicAdd(&curD[d], 1);
    csrPair[pd] = make_int2(s, e);
  }
}

// ---------------- tall-skinny GEMM: out[r,:] = X[r,:K] @ W[K,HOUT] ----------------
template <int K, int HOUT, bool SCALE, bool BIAS, bool BF16OUT>
__global__ __launch_bounds__(256)
void gemm_kernel(const float* __restrict__ X, const float* __restrict__ W,
                 const float* __restrict__ dis, const float* __restrict__ bias,
                 void* __restrict__ outv) {
  constexpr int TN = HOUT / 16;
  constexpr int NF4 = TN / 4;
  __shared__ float Ws[32 * HOUT];
  __shared__ float Xs[64][K + 4];
  const int tid = threadIdx.x;
  const int ct = tid & 15;
  const int rt = tid >> 4;
  const int rowBase = blockIdx.x * 64;

  constexpr int XF4 = 64 * K / 4 / 256;
#pragma unroll
  for (int i = 0; i < XF4; ++i) {
    int idx = tid + i * 256;
    int r = idx / (K / 4);
    int c = idx - r * (K / 4);
    int rg = rowBase + r;
    if (rg >= NNODES) rg = NNODES - 1;
    float4 v = *(const float4*)&X[(size_t)rg * K + c * 4];
    *(float4*)&Xs[r][c * 4] = v;
  }

  float4 acc[4][NF4] = {};

  constexpr int WF4 = 32 * HOUT / 4 / 256;
  for (int kc = 0; kc < K; kc += 32) {
    __syncthreads();
#pragma unroll
    for (int i = 0; i < WF4; ++i) {
      int idx = tid + i * 256;
      ((float4*)Ws)[idx] = *(const float4*)&W[(size_t)kc * HOUT + idx * 4];
    }
    __syncthreads();
#pragma unroll
    for (int k2 = 0; k2 < 32; ++k2) {
      float xv[4];
#pragma unroll
      for (int t = 0; t < 4; ++t) xv[t] = Xs[rt * 4 + t][kc + k2];
#pragma unroll
      for (int i = 0; i < NF4; ++i) {
        float4 w = *(const float4*)&Ws[k2 * HOUT + ct * TN + i * 4];
#pragma unroll
        for (int t = 0; t < 4; ++t) {
          acc[t][i].x = fmaf(xv[t], w.x, acc[t][i].x);
          acc[t][i].y = fmaf(xv[t], w.y, acc[t][i].y);
          acc[t][i].z = fmaf(xv[t], w.z, acc[t][i].z);
          acc[t][i].w = fmaf(xv[t], w.w, acc[t][i].w);
        }
      }
    }
  }

#pragma unroll
  for (int t = 0; t < 4; ++t) {
    int row = rowBase + rt * 4 + t;
    if (row >= NNODES) continue;
    float s = SCALE ? dis[row] : 1.0f;
#pragma unroll
    for (int i = 0; i < NF4; ++i) {
      int col = ct * TN + i * 4;
      float4 a = acc[t][i];
      a.x *= s; a.y *= s; a.z *= s; a.w *= s;
      if (BIAS) {
        float4 b = *(const float4*)&bias[col];
        a.x += b.x; a.y += b.y; a.z += b.z; a.w += b.w;
      }
      if (BF16OUT) {
        ushort4 u;
        u.x = f2bf(a.x); u.y = f2bf(a.y); u.z = f2bf(a.z); u.w = f2bf(a.w);
        *(ushort4*)&((unsigned short*)outv)[(size_t)row * HOUT + col] = u;
      } else {
        *(float4*)&((float*)outv)[(size_t)row * HOUT + col] = a;
      }
    }
  }
}

// ---------------- aggregation: one wave per node, 4-deep gather pipeline ----------------
template <int HOUT>
__global__ __launch_bounds__(256)
void agg_kernel(const float* __restrict__ hws, const int2* __restrict__ csrPair,
                const int* __restrict__ startA, const int* __restrict__ cnt,
                const float* __restrict__ dis, const float* __restrict__ bias,
                float* __restrict__ out) {
  int gid = blockIdx.x * 256 + threadIdx.x;
  int v = gid >> 6;
  int lane = gid & 63;
  constexpr int PER = HOUT / 64;
  float acc[PER];
  if constexpr (PER == 2) {
    float2 o = *(const float2*)&hws[(size_t)v * HOUT + lane * 2];
    acc[0] = o.x; acc[1] = o.y;
  } else {
    acc[0] = hws[(size_t)v * HOUT + lane];
  }
  int s0 = startA[v], c = cnt[v];
  for (int base = 0; base < c; base += 64) {
    int rem = c - base;
    int m = rem < 64 ? rem : 64;
    int idx = 0;
    if (lane < m) idx = csrPair[s0 + base + lane].x;
    int j = 0;
    for (; j + 4 <= m; j += 4) {
      int u0 = __shfl(idx, j);
      int u1 = __shfl(idx, j + 1);
      int u2 = __shfl(idx, j + 2);
      int u3 = __shfl(idx, j + 3);
      if constexpr (PER == 2) {
        float2 r0 = *(const float2*)&hws[(size_t)u0 * HOUT + lane * 2];
        float2 r1 = *(const float2*)&hws[(size_t)u1 * HOUT + lane * 2];
        float2 r2 = *(const float2*)&hws[(size_t)u2 * HOUT + lane * 2];
        float2 r3 = *(const float2*)&hws[(size_t)u3 * HOUT + lane * 2];
        acc[0] += r0.x + r1.x + r2.x + r3.x;
        acc[1] += r0.y + r1.y + r2.y + r3.y;
      } else {
        float r0 = hws[(size_t)u0 * HOUT + lane];
        float r1 = hws[(size_t)u1 * HOUT + lane];
        float r2 = hws[(size_t)u2 * HOUT + lane];
        float r3 = hws[(size_t)u3 * HOUT + lane];
        acc[0] += (r0 + r1) + (r2 + r3);
      }
    }
    for (; j < m; ++j) {
      int u = __shfl(idx, j);
      if constexpr (PER == 2) {
        float2 r = *(const float2*)&hws[(size_t)u * HOUT + lane * 2];
        acc[0] += r.x; acc[1] += r.y;
      } else {
        acc[0] += hws[(size_t)u * HOUT + lane];
      }
    }
  }
  float d = dis[v];
#pragma unroll
  for (int i = 0; i < PER; ++i) {
    float r = fmaf(d, acc[i], bias[lane * PER + i]);
    out[(size_t)v * HOUT + lane * PER + i] = r > 0.0f ? r : 0.0f;
  }
}

// ---------------- edge classifier: one wave per DST node ----------------
// B row loaded once into registers; stream over incoming edges gathering A[src].
__global__ __launch_bounds__(256)
void edge_kernel(const unsigned short* __restrict__ A, const unsigned short* __restrict__ B,
                 const int2* __restrict__ csrPair,
                 const int* __restrict__ startD, const int* __restrict__ cntD,
                 const float* __restrict__ lw2, const float* __restrict__ lb2,
                 float* __restrict__ out) {
  int gid = blockIdx.x * 256 + threadIdx.x;
  int v = gid >> 6;
  int lane = gid & 63;
  ushort4 bv = *(const ushort4*)&B[(size_t)v * 256 + lane * 4];
  float q0 = bf2f(bv.x), q1 = bf2f(bv.y), q2 = bf2f(bv.z), q3 = bf2f(bv.w);
  float4 w = *(const float4*)&lw2[lane * 4];
  float lb = lb2[0];
  int s0 = startD[v], c = cntD[v];
  for (int base = 0; base < c; base += 64) {
    int rem = c - base;
    int m = rem < 64 ? rem : 64;
    int sj = 0, ej = 0;
    if (lane < m) {
      int2 p = csrPair[s0 + base + lane];
      sj = p.x; ej = p.y;
    }
    for (int j = 0; j < m; j += 2) {
      bool two = (j + 1 < m);
      int src0 = __shfl(sj, j);
      int e0   = __shfl(ej, j);
      int src1 = __shfl(sj, (j + 1) & 63);
      int e1   = __shfl(ej, (j + 1) & 63);
      ushort4 a0 = *(const ushort4*)&A[(size_t)src0 * 256 + lane * 4];
      ushort4 a1 = *(const ushort4*)&A[(size_t)src1 * 256 + lane * 4];
      float h00 = q0 + bf2f(a0.x), h01 = q1 + bf2f(a0.y), h02 = q2 + bf2f(a0.z), h03 = q3 + bf2f(a0.w);
      float h10 = q0 + bf2f(a1.x), h11 = q1 + bf2f(a1.y), h12 = q2 + bf2f(a1.z), h13 = q3 + bf2f(a1.w);
      h00 = h00 > 0.0f ? h00 : 0.0f; h01 = h01 > 0.0f ? h01 : 0.0f;
      h02 = h02 > 0.0f ? h02 : 0.0f; h03 = h03 > 0.0f ? h03 : 0.0f;
      h10 = h10 > 0.0f ? h10 : 0.0f; h11 = h11 > 0.0f ? h11 : 0.0f;
      h12 = h12 > 0.0f ? h12 : 0.0f; h13 = h13 > 0.0f ? h13 : 0.0f;
      float acc0 = fmaf(h03, w.w, fmaf(h02, w.z, fmaf(h01, w.y, h00 * w.x)));
      float acc1 = fmaf(h13, w.w, fmaf(h12, w.z, fmaf(h11, w.y, h10 * w.x)));
#pragma unroll
      for (int off = 32; off; off >>= 1) {
        acc0 += __shfl_xor(acc0, off);
        acc1 += __shfl_xor(acc1, off);
      }
      if (lane == 0) {
        out[e0] = 1.0f / (1.0f + expf(-(acc0 + lb)));
        if (two) out[e1] = 1.0f / (1.0f + expf(-(acc1 + lb)));
      }
    }
  }
}

extern "C" void kernel_launch(void* const* d_in, const int* in_sizes, int n_in,
                              void* d_out, int out_size, void* d_ws, size_t ws_size,
                              hipStream_t stream) {
  const float* x   = (const float*)d_in[0];
  const int*   ei  = (const int*)d_in[1];
  const float* W0  = (const float*)d_in[2];
  const float* b0  = (const float*)d_in[3];
  const float* W1  = (const float*)d_in[4];
  const float* b1  = (const float*)d_in[5];
  const float* W2  = (const float*)d_in[6];
  const float* b2  = (const float*)d_in[7];
  const float* lw1 = (const float*)d_in[8];
  const float* lb1 = (const float*)d_in[9];
  const float* lw2 = (const float*)d_in[10];
  const float* lb2 = (const float*)d_in[11];
  float* out = (float*)d_out;
  const int* src = ei;
  const int* dst = ei + NEDGES;

  char* ws = (char*)d_ws;
  size_t off = 0;
  auto alloc = [&](size_t bytes) -> void* {
    void* p = ws + off;
    off += (bytes + 255) & ~(size_t)255;
    return p;
  };
  int*   cntD   = (int*)alloc((size_t)NNODES * 4);
  int*   startD = (int*)alloc((size_t)NNODES * 4);
  int*   curD   = (int*)alloc((size_t)NNODES * 4);
  float* dis    = (float*)alloc((size_t)NNODES * 4);
  int*   totD   = (int*)alloc(256);
  int2*  csrPair= (int2*)alloc((size_t)NEDGES * 8);
  float* P      = (float*)alloc((size_t)NNODES * 128 * 4);
  float* Q      = (float*)alloc((size_t)NNODES * 128 * 4);
  unsigned short* Abuf = (unsigned short*)alloc((size_t)NNODES * 256 * 2);
  unsigned short* Bbuf = (unsigned short*)alloc((size_t)NNODES * 256 * 2);

  hipMemsetAsync(cntD, 0, (size_t)NNODES * 4, stream);
  hipMemsetAsync(totD, 0, 256, stream);
  count_kernel<<<(NEDGES + 255) / 256, 256, 0, stream>>>(dst, cntD);
  alloc_kernel<<<(NNODES + 255) / 256, 256, 0, stream>>>(cntD, startD, curD, dis, totD);
  fill_kernel<<<(NEDGES + 255) / 256, 256, 0, stream>>>(src, dst, curD, csrPair);

  const int GB = (NNODES + 63) / 64;   // gemm blocks
  const int AB = (NNODES * 64) / 256;  // one wave per node (exact: 25000)

  gemm_kernel<128, 128, true, false, false><<<GB, 256, 0, stream>>>(x, W0, dis, nullptr, P);
  agg_kernel<128><<<AB, 256, 0, stream>>>(P, csrPair, startD, cntD, dis, b0, Q);
  gemm_kernel<128, 128, true, false, false><<<GB, 256, 0, stream>>>(Q, W1, dis, nullptr, P);
  agg_kernel<128><<<AB, 256, 0, stream>>>(P, csrPair, startD, cntD, dis, b1, Q);
  gemm_kernel<128, 64, true, false, false><<<GB, 256, 0, stream>>>(Q, W2, dis, nullptr, P);
  agg_kernel<64><<<AB, 256, 0, stream>>>(P, csrPair, startD, cntD, dis, b2, Q);

  // edge MLP split: A = z@lw1[0:64,:] + lb1 ; B = z@lw1[64:128,:]
  gemm_kernel<64, 256, false, true, true><<<GB, 256, 0, stream>>>(Q, lw1, nullptr, lb1, Abuf);
  gemm_kernel<64, 256, false, false, true><<<GB, 256, 0, stream>>>(Q, lw1 + 64 * 256, nullptr, nullptr, Bbuf);

  // per-edge (grouped by dst): gather A[src], resident B[dst], relu-dot lw2, sigmoid
  edge_kernel<<<AB, 256, 0, stream>>>(Abuf, Bbuf, csrPair, startD, cntD, lw2, lb2, out);
}

// Round 5
// 923.553 us; speedup vs baseline: 1.2928x; 1.0337x over previous
//
#include <hip/hip_runtime.h>

#define NNODES 100000
#define NEDGES 1600000

__device__ __forceinline__ unsigned short f2bf(float f) {
  unsigned int u = __float_as_uint(f);
  u = (u + 0x7FFFu + ((u >> 16) & 1u)) >> 16;
  return (unsigned short)u;
}
__device__ __forceinline__ float bf2f(unsigned short h) {
  return __uint_as_float(((unsigned int)h) << 16);
}

// ---------------- CSR build (dst side only) ----------------
__global__ void count_kernel(const int* __restrict__ dst, int* __restrict__ cntD) {
  int e = blockIdx.x * 256 + threadIdx.x;
  if (e < NEDGES) atomicAdd(&cntD[dst[e]], 1);
}

__global__ void alloc_kernel(const int* __restrict__ cntD, int* __restrict__ startD,
                             int* __restrict__ curD, float* __restrict__ dis,
                             int* __restrict__ totD) {
  int v = blockIdx.x * 256 + threadIdx.x;
  if (v < NNODES) {
    int c = cntD[v];
    int s = atomicAdd(totD, c);
    startD[v] = s;
    curD[v] = s;
    dis[v] = rsqrtf((float)(c + 1));  // deg = in-degree + self loop
  }
}

// one 8B scattered store per edge: (src, eid) packed
__global__ void fill_kernel(const int* __restrict__ src, const int* __restrict__ dst,
                            int* __restrict__ curD, int2* __restrict__ csrPair) {
  int e = blockIdx.x * 256 + threadIdx.x;
  if (e < NEDGES) {
    int s = src[e], d = dst[e];
    int pd = atomicAdd(&curD[d], 1);
    csrPair[pd] = make_int2(s, e);
  }
}

// ---------------- tall-skinny GEMM: out[r,:] = X[r,:K] @ W[K,HOUT] ----------------
template <int K, int HOUT, bool SCALE, bool BIAS, bool BF16OUT>
__global__ __launch_bounds__(256)
void gemm_kernel(const float* __restrict__ X, const float* __restrict__ W,
                 const float* __restrict__ dis, const float* __restrict__ bias,
                 void* __restrict__ outv) {
  constexpr int TN = HOUT / 16;
  constexpr int NF4 = TN / 4;
  __shared__ float Ws[32 * HOUT];
  __shared__ float Xs[64][K + 4];
  const int tid = threadIdx.x;
  const int ct = tid & 15;
  const int rt = tid >> 4;
  const int rowBase = blockIdx.x * 64;

  constexpr int XF4 = 64 * K / 4 / 256;
#pragma unroll
  for (int i = 0; i < XF4; ++i) {
    int idx = tid + i * 256;
    int r = idx / (K / 4);
    int c = idx - r * (K / 4);
    int rg = rowBase + r;
    if (rg >= NNODES) rg = NNODES - 1;
    float4 v = *(const float4*)&X[(size_t)rg * K + c * 4];
    *(float4*)&Xs[r][c * 4] = v;
  }

  float4 acc[4][NF4] = {};

  constexpr int WF4 = 32 * HOUT / 4 / 256;
  for (int kc = 0; kc < K; kc += 32) {
    __syncthreads();
#pragma unroll
    for (int i = 0; i < WF4; ++i) {
      int idx = tid + i * 256;
      ((float4*)Ws)[idx] = *(const float4*)&W[(size_t)kc * HOUT + idx * 4];
    }
    __syncthreads();
#pragma unroll
    for (int k2 = 0; k2 < 32; ++k2) {
      float xv[4];
#pragma unroll
      for (int t = 0; t < 4; ++t) xv[t] = Xs[rt * 4 + t][kc + k2];
#pragma unroll
      for (int i = 0; i < NF4; ++i) {
        float4 w = *(const float4*)&Ws[k2 * HOUT + ct * TN + i * 4];
#pragma unroll
        for (int t = 0; t < 4; ++t) {
          acc[t][i].x = fmaf(xv[t], w.x, acc[t][i].x);
          acc[t][i].y = fmaf(xv[t], w.y, acc[t][i].y);
          acc[t][i].z = fmaf(xv[t], w.z, acc[t][i].z);
          acc[t][i].w = fmaf(xv[t], w.w, acc[t][i].w);
        }
      }
    }
  }

#pragma unroll
  for (int t = 0; t < 4; ++t) {
    int row = rowBase + rt * 4 + t;
    if (row >= NNODES) continue;
    float s = SCALE ? dis[row] : 1.0f;
#pragma unroll
    for (int i = 0; i < NF4; ++i) {
      int col = ct * TN + i * 4;
      float4 a = acc[t][i];
      a.x *= s; a.y *= s; a.z *= s; a.w *= s;
      if (BIAS) {
        float4 b = *(const float4*)&bias[col];
        a.x += b.x; a.y += b.y; a.z += b.z; a.w += b.w;
      }
      if (BF16OUT) {
        ushort4 u;
        u.x = f2bf(a.x); u.y = f2bf(a.y); u.z = f2bf(a.z); u.w = f2bf(a.w);
        *(ushort4*)&((unsigned short*)outv)[(size_t)row * HOUT + col] = u;
      } else {
        *(float4*)&((float*)outv)[(size_t)row * HOUT + col] = a;
      }
    }
  }
}

// ---------------- aggregation: one wave per node, 4-deep gather pipeline ----------------
template <int HOUT>
__global__ __launch_bounds__(256)
void agg_kernel(const float* __restrict__ hws, const int2* __restrict__ csrPair,
                const int* __restrict__ startA, const int* __restrict__ cnt,
                const float* __restrict__ dis, const float* __restrict__ bias,
                float* __restrict__ out) {
  int gid = blockIdx.x * 256 + threadIdx.x;
  int v = gid >> 6;
  int lane = gid & 63;
  constexpr int PER = HOUT / 64;
  float acc[PER];
  if constexpr (PER == 2) {
    float2 o = *(const float2*)&hws[(size_t)v * HOUT + lane * 2];
    acc[0] = o.x; acc[1] = o.y;
  } else {
    acc[0] = hws[(size_t)v * HOUT + lane];
  }
  int s0 = startA[v], c = cnt[v];
  for (int base = 0; base < c; base += 64) {
    int rem = c - base;
    int m = rem < 64 ? rem : 64;
    int idx = 0;
    if (lane < m) idx = csrPair[s0 + base + lane].x;
    int j = 0;
    for (; j + 4 <= m; j += 4) {
      int u0 = __shfl(idx, j);
      int u1 = __shfl(idx, j + 1);
      int u2 = __shfl(idx, j + 2);
      int u3 = __shfl(idx, j + 3);
      if constexpr (PER == 2) {
        float2 r0 = *(const float2*)&hws[(size_t)u0 * HOUT + lane * 2];
        float2 r1 = *(const float2*)&hws[(size_t)u1 * HOUT + lane * 2];
        float2 r2 = *(const float2*)&hws[(size_t)u2 * HOUT + lane * 2];
        float2 r3 = *(const float2*)&hws[(size_t)u3 * HOUT + lane * 2];
        acc[0] += r0.x + r1.x + r2.x + r3.x;
        acc[1] += r0.y + r1.y + r2.y + r3.y;
      } else {
        float r0 = hws[(size_t)u0 * HOUT + lane];
        float r1 = hws[(size_t)u1 * HOUT + lane];
        float r2 = hws[(size_t)u2 * HOUT + lane];
        float r3 = hws[(size_t)u3 * HOUT + lane];
        acc[0] += (r0 + r1) + (r2 + r3);
      }
    }
    for (; j < m; ++j) {
      int u = __shfl(idx, j);
      if constexpr (PER == 2) {
        float2 r = *(const float2*)&hws[(size_t)u * HOUT + lane * 2];
        acc[0] += r.x; acc[1] += r.y;
      } else {
        acc[0] += hws[(size_t)u * HOUT + lane];
      }
    }
  }
  float d = dis[v];
#pragma unroll
  for (int i = 0; i < PER; ++i) {
    float r = fmaf(d, acc[i], bias[lane * PER + i]);
    out[(size_t)v * HOUT + lane * PER + i] = r > 0.0f ? r : 0.0f;
  }
}

// ---------------- edge classifier: one wave per DST node, 16-lane groups ----------------
// 4 edges per iteration; lane owns a 16-dim slice of the 256-dim relu-dot.
// Writes raw logits; sigmoid applied in a separate elementwise pass.
__global__ __launch_bounds__(256)
void edge_kernel(const unsigned short* __restrict__ A, const unsigned short* __restrict__ B,
                 const int2* __restrict__ csrPair,
                 const int* __restrict__ startD, const int* __restrict__ cntD,
                 const float* __restrict__ lw2,
                 float* __restrict__ out) {
  int gid = blockIdx.x * 256 + threadIdx.x;
  int v = gid >> 6;
  int lane = gid & 63;
  int sub = lane & 15;   // dim-slice owner within group
  // B slice (16 bf16 -> 16 f32) and lw2 slice, resident in registers
  const unsigned int* Brow = (const unsigned int*)&B[(size_t)v * 256 + sub * 16];
  uint4 br0 = *(const uint4*)Brow;
  uint4 br1 = *(const uint4*)(Brow + 4);
  float bq[16];
  {
    unsigned int u[8] = {br0.x, br0.y, br0.z, br0.w, br1.x, br1.y, br1.z, br1.w};
#pragma unroll
    for (int i = 0; i < 8; ++i) {
      bq[2 * i]     = __uint_as_float(u[i] << 16);
      bq[2 * i + 1] = __uint_as_float(u[i] & 0xffff0000u);
    }
  }
  float wv[16];
#pragma unroll
  for (int i = 0; i < 4; ++i) {
    float4 w4 = *(const float4*)&lw2[sub * 16 + i * 4];
    wv[4 * i] = w4.x; wv[4 * i + 1] = w4.y; wv[4 * i + 2] = w4.z; wv[4 * i + 3] = w4.w;
  }

  int s0 = startD[v], c = cntD[v];
  for (int base = 0; base < c; base += 64) {
    int rem = c - base;
    int m = rem < 64 ? rem : 64;
    int sj = 0, ej = 0;
    if (lane < m) {
      int2 p = csrPair[s0 + base + lane];
      sj = p.x; ej = p.y;
    }
    for (int j = 0; j < m; j += 4) {
      int ls = j + (lane >> 4);              // group g handles edge j+g
      int lsc = ls < m ? ls : m - 1;         // clamp tail (duplicate row, same lines)
      int s = __shfl(sj, lsc);               // per-lane lane index -> bpermute
      int e = __shfl(ej, lsc);
      const unsigned int* Arow = (const unsigned int*)&A[(size_t)(unsigned)s * 256 + sub * 16];
      uint4 a0 = *(const uint4*)Arow;
      uint4 a1 = *(const uint4*)(Arow + 4);
      unsigned int au[8] = {a0.x, a0.y, a0.z, a0.w, a1.x, a1.y, a1.z, a1.w};
      float p0 = 0.f, p1 = 0.f, p2 = 0.f, p3 = 0.f;
#pragma unroll
      for (int i = 0; i < 4; ++i) {
        float hlo0 = __uint_as_float(au[2 * i] << 16) + bq[4 * i];
        float hhi0 = __uint_as_float(au[2 * i] & 0xffff0000u) + bq[4 * i + 1];
        float hlo1 = __uint_as_float(au[2 * i + 1] << 16) + bq[4 * i + 2];
        float hhi1 = __uint_as_float(au[2 * i + 1] & 0xffff0000u) + bq[4 * i + 3];
        hlo0 = hlo0 > 0.f ? hlo0 : 0.f;
        hhi0 = hhi0 > 0.f ? hhi0 : 0.f;
        hlo1 = hlo1 > 0.f ? hlo1 : 0.f;
        hhi1 = hhi1 > 0.f ? hhi1 : 0.f;
        p0 = fmaf(hlo0, wv[4 * i], p0);
        p1 = fmaf(hhi0, wv[4 * i + 1], p1);
        p2 = fmaf(hlo1, wv[4 * i + 2], p2);
        p3 = fmaf(hhi1, wv[4 * i + 3], p3);
      }
      float acc = (p0 + p1) + (p2 + p3);
      acc += __shfl_xor(acc, 1);
      acc += __shfl_xor(acc, 2);
      acc += __shfl_xor(acc, 4);
      acc += __shfl_xor(acc, 8);
      if (ls < m && sub == 0) out[e] = acc;  // raw logit
    }
  }
}

// ---------------- sigmoid pass over logits ----------------
__global__ __launch_bounds__(256)
void sigmoid_kernel(float* __restrict__ out, const float* __restrict__ lb2) {
  int i = blockIdx.x * 256 + threadIdx.x;
  if (i < NEDGES) {
    float lb = lb2[0];
    out[i] = 1.0f / (1.0f + expf(-(out[i] + lb)));
  }
}

extern "C" void kernel_launch(void* const* d_in, const int* in_sizes, int n_in,
                              void* d_out, int out_size, void* d_ws, size_t ws_size,
                              hipStream_t stream) {
  const float* x   = (const float*)d_in[0];
  const int*   ei  = (const int*)d_in[1];
  const float* W0  = (const float*)d_in[2];
  const float* b0  = (const float*)d_in[3];
  const float* W1  = (const float*)d_in[4];
  const float* b1  = (const float*)d_in[5];
  const float* W2  = (const float*)d_in[6];
  const float* b2  = (const float*)d_in[7];
  const float* lw1 = (const float*)d_in[8];
  const float* lb1 = (const float*)d_in[9];
  const float* lw2 = (const float*)d_in[10];
  const float* lb2 = (const float*)d_in[11];
  float* out = (float*)d_out;
  const int* src = ei;
  const int* dst = ei + NEDGES;

  char* ws = (char*)d_ws;
  size_t off = 0;
  auto alloc = [&](size_t bytes) -> void* {
    void* p = ws + off;
    off += (bytes + 255) & ~(size_t)255;
    return p;
  };
  int*   cntD   = (int*)alloc((size_t)NNODES * 4);
  int*   startD = (int*)alloc((size_t)NNODES * 4);
  int*   curD   = (int*)alloc((size_t)NNODES * 4);
  float* dis    = (float*)alloc((size_t)NNODES * 4);
  int*   totD   = (int*)alloc(256);
  int2*  csrPair= (int2*)alloc((size_t)NEDGES * 8);
  float* P      = (float*)alloc((size_t)NNODES * 128 * 4);
  float* Q      = (float*)alloc((size_t)NNODES * 128 * 4);
  unsigned short* Abuf = (unsigned short*)alloc((size_t)NNODES * 256 * 2);
  unsigned short* Bbuf = (unsigned short*)alloc((size_t)NNODES * 256 * 2);

  hipMemsetAsync(cntD, 0, (size_t)NNODES * 4, stream);
  hipMemsetAsync(totD, 0, 256, stream);
  count_kernel<<<(NEDGES + 255) / 256, 256, 0, stream>>>(dst, cntD);
  alloc_kernel<<<(NNODES + 255) / 256, 256, 0, stream>>>(cntD, startD, curD, dis, totD);
  fill_kernel<<<(NEDGES + 255) / 256, 256, 0, stream>>>(src, dst, curD, csrPair);

  const int GB = (NNODES + 63) / 64;   // gemm blocks
  const int AB = (NNODES * 64) / 256;  // one wave per node (exact: 25000)

  gemm_kernel<128, 128, true, false, false><<<GB, 256, 0, stream>>>(x, W0, dis, nullptr, P);
  agg_kernel<128><<<AB, 256, 0, stream>>>(P, csrPair, startD, cntD, dis, b0, Q);
  gemm_kernel<128, 128, true, false, false><<<GB, 256, 0, stream>>>(Q, W1, dis, nullptr, P);
  agg_kernel<128><<<AB, 256, 0, stream>>>(P, csrPair, startD, cntD, dis, b1, Q);
  gemm_kernel<128, 64, true, false, false><<<GB, 256, 0, stream>>>(Q, W2, dis, nullptr, P);
  agg_kernel<64><<<AB, 256, 0, stream>>>(P, csrPair, startD, cntD, dis, b2, Q);

  // edge MLP split: A = z@lw1[0:64,:] + lb1 ; B = z@lw1[64:128,:]
  gemm_kernel<64, 256, false, true, true><<<GB, 256, 0, stream>>>(Q, lw1, nullptr, lb1, Abuf);
  gemm_kernel<64, 256, false, false, true><<<GB, 256, 0, stream>>>(Q, lw1 + 64 * 256, nullptr, nullptr, Bbuf);

  // per-edge (grouped by dst): resident B[dst] slice, gather A[src], relu-dot lw2 -> logit
  edge_kernel<<<AB, 256, 0, stream>>>(Abuf, Bbuf, csrPair, startD, cntD, lw2, out);
  sigmoid_kernel<<<(NEDGES + 255) / 256, 256, 0, stream>>>(out, lb2);
}

// Round 6
// 821.209 us; speedup vs baseline: 1.4539x; 1.1246x over previous
//
#include <hip/hip_runtime.h>

#define NNODES 100000
#define NEDGES 1600000

__device__ __forceinline__ unsigned short f2bf(float f) {
  unsigned int u = __float_as_uint(f);
  u = (u + 0x7FFFu + ((u >> 16) & 1u)) >> 16;
  return (unsigned short)u;
}
__device__ __forceinline__ float bf2f(unsigned short h) {
  return __uint_as_float(((unsigned int)h) << 16);
}

// ---------------- CSR build (dst side only) ----------------
__global__ void count_kernel(const int* __restrict__ dst, int* __restrict__ cntD) {
  int e = blockIdx.x * 256 + threadIdx.x;
  if (e < NEDGES) atomicAdd(&cntD[dst[e]], 1);
}

__global__ void alloc_kernel(const int* __restrict__ cntD, int* __restrict__ startD,
                             int* __restrict__ curD, float* __restrict__ dis,
                             int* __restrict__ totD) {
  int v = blockIdx.x * 256 + threadIdx.x;
  if (v < NNODES) {
    int c = cntD[v];
    int s = atomicAdd(totD, c);
    startD[v] = s;
    curD[v] = s;
    dis[v] = rsqrtf((float)(c + 1));  // deg = in-degree + self loop
  }
}

// one 8B scattered store per edge: (src, eid) packed
__global__ void fill_kernel(const int* __restrict__ src, const int* __restrict__ dst,
                            int* __restrict__ curD, int2* __restrict__ csrPair) {
  int e = blockIdx.x * 256 + threadIdx.x;
  if (e < NEDGES) {
    int s = src[e], d = dst[e];
    int pd = atomicAdd(&curD[d], 1);
    csrPair[pd] = make_int2(s, e);
  }
}

// ---------------- tall-skinny GEMM: out[r,:] = X[r,:K] @ W[K,HOUT] ----------------
template <int K, int HOUT, bool SCALE, bool BIAS, bool BF16OUT>
__global__ __launch_bounds__(256)
void gemm_kernel(const float* __restrict__ X, const float* __restrict__ W,
                 const float* __restrict__ dis, const float* __restrict__ bias,
                 void* __restrict__ outv) {
  constexpr int TN = HOUT / 16;
  constexpr int NF4 = TN / 4;
  __shared__ float Ws[32 * HOUT];
  __shared__ float Xs[64][K + 4];
  const int tid = threadIdx.x;
  const int ct = tid & 15;
  const int rt = tid >> 4;
  const int rowBase = blockIdx.x * 64;

  constexpr int XF4 = 64 * K / 4 / 256;
#pragma unroll
  for (int i = 0; i < XF4; ++i) {
    int idx = tid + i * 256;
    int r = idx / (K / 4);
    int c = idx - r * (K / 4);
    int rg = rowBase + r;
    if (rg >= NNODES) rg = NNODES - 1;
    float4 v = *(const float4*)&X[(size_t)rg * K + c * 4];
    *(float4*)&Xs[r][c * 4] = v;
  }

  float4 acc[4][NF4] = {};

  constexpr int WF4 = 32 * HOUT / 4 / 256;
  for (int kc = 0; kc < K; kc += 32) {
    __syncthreads();
#pragma unroll
    for (int i = 0; i < WF4; ++i) {
      int idx = tid + i * 256;
      ((float4*)Ws)[idx] = *(const float4*)&W[(size_t)kc * HOUT + idx * 4];
    }
    __syncthreads();
#pragma unroll
    for (int k2 = 0; k2 < 32; ++k2) {
      float xv[4];
#pragma unroll
      for (int t = 0; t < 4; ++t) xv[t] = Xs[rt * 4 + t][kc + k2];
#pragma unroll
      for (int i = 0; i < NF4; ++i) {
        float4 w = *(const float4*)&Ws[k2 * HOUT + ct * TN + i * 4];
#pragma unroll
        for (int t = 0; t < 4; ++t) {
          acc[t][i].x = fmaf(xv[t], w.x, acc[t][i].x);
          acc[t][i].y = fmaf(xv[t], w.y, acc[t][i].y);
          acc[t][i].z = fmaf(xv[t], w.z, acc[t][i].z);
          acc[t][i].w = fmaf(xv[t], w.w, acc[t][i].w);
        }
      }
    }
  }

#pragma unroll
  for (int t = 0; t < 4; ++t) {
    int row = rowBase + rt * 4 + t;
    if (row >= NNODES) continue;
    float s = SCALE ? dis[row] : 1.0f;
#pragma unroll
    for (int i = 0; i < NF4; ++i) {
      int col = ct * TN + i * 4;
      float4 a = acc[t][i];
      a.x *= s; a.y *= s; a.z *= s; a.w *= s;
      if (BIAS) {
        float4 b = *(const float4*)&bias[col];
        a.x += b.x; a.y += b.y; a.z += b.z; a.w += b.w;
      }
      if (BF16OUT) {
        ushort4 u;
        u.x = f2bf(a.x); u.y = f2bf(a.y); u.z = f2bf(a.z); u.w = f2bf(a.w);
        *(ushort4*)&((unsigned short*)outv)[(size_t)row * HOUT + col] = u;
      } else {
        *(float4*)&((float*)outv)[(size_t)row * HOUT + col] = a;
      }
    }
  }
}

// ---------------- aggregation: one wave per node, bf16 messages, 4-deep pipeline ----------------
// out[v] = relu(dis[v] * (P[v] + sum_{u in bucket} P[u]) + bias), P in bf16
template <int HOUT>
__global__ __launch_bounds__(256)
void agg_kernel(const unsigned short* __restrict__ hws, const int2* __restrict__ csrPair,
                const int* __restrict__ startA, const int* __restrict__ cnt,
                const float* __restrict__ dis, const float* __restrict__ bias,
                float* __restrict__ out) {
  int gid = blockIdx.x * 256 + threadIdx.x;
  int v = gid >> 6;
  int lane = gid & 63;
  constexpr int PER = HOUT / 64;
  float acc0 = 0.0f, acc1 = 0.0f;
  if constexpr (PER == 2) {
    unsigned int o = *(const unsigned int*)&hws[(size_t)v * HOUT + lane * 2];
    acc0 = __uint_as_float(o << 16);
    acc1 = __uint_as_float(o & 0xffff0000u);
  } else {
    acc0 = bf2f(hws[(size_t)v * HOUT + lane]);
  }
  int s0 = startA[v], c = cnt[v];
  for (int base = 0; base < c; base += 64) {
    int rem = c - base;
    int m = rem < 64 ? rem : 64;
    int idx = 0;
    if (lane < m) idx = csrPair[s0 + base + lane].x;
    int j = 0;
    for (; j + 4 <= m; j += 4) {
      int u0 = __shfl(idx, j);
      int u1 = __shfl(idx, j + 1);
      int u2 = __shfl(idx, j + 2);
      int u3 = __shfl(idx, j + 3);
      if constexpr (PER == 2) {
        unsigned int r0 = *(const unsigned int*)&hws[(size_t)u0 * HOUT + lane * 2];
        unsigned int r1 = *(const unsigned int*)&hws[(size_t)u1 * HOUT + lane * 2];
        unsigned int r2 = *(const unsigned int*)&hws[(size_t)u2 * HOUT + lane * 2];
        unsigned int r3 = *(const unsigned int*)&hws[(size_t)u3 * HOUT + lane * 2];
        acc0 += __uint_as_float(r0 << 16) + __uint_as_float(r1 << 16) +
                __uint_as_float(r2 << 16) + __uint_as_float(r3 << 16);
        acc1 += __uint_as_float(r0 & 0xffff0000u) + __uint_as_float(r1 & 0xffff0000u) +
                __uint_as_float(r2 & 0xffff0000u) + __uint_as_float(r3 & 0xffff0000u);
      } else {
        float r0 = bf2f(hws[(size_t)u0 * HOUT + lane]);
        float r1 = bf2f(hws[(size_t)u1 * HOUT + lane]);
        float r2 = bf2f(hws[(size_t)u2 * HOUT + lane]);
        float r3 = bf2f(hws[(size_t)u3 * HOUT + lane]);
        acc0 += (r0 + r1) + (r2 + r3);
      }
    }
    for (; j < m; ++j) {
      int u = __shfl(idx, j);
      if constexpr (PER == 2) {
        unsigned int r = *(const unsigned int*)&hws[(size_t)u * HOUT + lane * 2];
        acc0 += __uint_as_float(r << 16);
        acc1 += __uint_as_float(r & 0xffff0000u);
      } else {
        acc0 += bf2f(hws[(size_t)u * HOUT + lane]);
      }
    }
  }
  float d = dis[v];
  if constexpr (PER == 2) {
    float o0 = fmaf(d, acc0, bias[lane * 2]);
    float o1 = fmaf(d, acc1, bias[lane * 2 + 1]);
    float2 o = make_float2(o0 > 0.0f ? o0 : 0.0f, o1 > 0.0f ? o1 : 0.0f);
    *(float2*)&out[(size_t)v * HOUT + lane * 2] = o;
  } else {
    float o0 = fmaf(d, acc0, bias[lane]);
    out[(size_t)v * HOUT + lane] = o0 > 0.0f ? o0 : 0.0f;
  }
}

// ---------------- edge classifier: one wave per DST node, 16-lane groups ----------------
__global__ __launch_bounds__(256)
void edge_kernel(const unsigned short* __restrict__ A, const unsigned short* __restrict__ B,
                 const int2* __restrict__ csrPair,
                 const int* __restrict__ startD, const int* __restrict__ cntD,
                 const float* __restrict__ lw2,
                 float* __restrict__ out) {
  int gid = blockIdx.x * 256 + threadIdx.x;
  int v = gid >> 6;
  int lane = gid & 63;
  int sub = lane & 15;   // dim-slice owner within group
  const unsigned int* Brow = (const unsigned int*)&B[(size_t)v * 256 + sub * 16];
  uint4 br0 = *(const uint4*)Brow;
  uint4 br1 = *(const uint4*)(Brow + 4);
  float bq[16];
  {
    unsigned int u[8] = {br0.x, br0.y, br0.z, br0.w, br1.x, br1.y, br1.z, br1.w};
#pragma unroll
    for (int i = 0; i < 8; ++i) {
      bq[2 * i]     = __uint_as_float(u[i] << 16);
      bq[2 * i + 1] = __uint_as_float(u[i] & 0xffff0000u);
    }
  }
  float wv[16];
#pragma unroll
  for (int i = 0; i < 4; ++i) {
    float4 w4 = *(const float4*)&lw2[sub * 16 + i * 4];
    wv[4 * i] = w4.x; wv[4 * i + 1] = w4.y; wv[4 * i + 2] = w4.z; wv[4 * i + 3] = w4.w;
  }

  int s0 = startD[v], c = cntD[v];
  for (int base = 0; base < c; base += 64) {
    int rem = c - base;
    int m = rem < 64 ? rem : 64;
    int sj = 0, ej = 0;
    if (lane < m) {
      int2 p = csrPair[s0 + base + lane];
      sj = p.x; ej = p.y;
    }
    for (int j = 0; j < m; j += 4) {
      int ls = j + (lane >> 4);              // group g handles edge j+g
      int lsc = ls < m ? ls : m - 1;         // clamp tail (duplicate row, same lines)
      int s = __shfl(sj, lsc);
      int e = __shfl(ej, lsc);
      const unsigned int* Arow = (const unsigned int*)&A[(size_t)(unsigned)s * 256 + sub * 16];
      uint4 a0 = *(const uint4*)Arow;
      uint4 a1 = *(const uint4*)(Arow + 4);
      unsigned int au[8] = {a0.x, a0.y, a0.z, a0.w, a1.x, a1.y, a1.z, a1.w};
      float p0 = 0.f, p1 = 0.f, p2 = 0.f, p3 = 0.f;
#pragma unroll
      for (int i = 0; i < 4; ++i) {
        float hlo0 = __uint_as_float(au[2 * i] << 16) + bq[4 * i];
        float hhi0 = __uint_as_float(au[2 * i] & 0xffff0000u) + bq[4 * i + 1];
        float hlo1 = __uint_as_float(au[2 * i + 1] << 16) + bq[4 * i + 2];
        float hhi1 = __uint_as_float(au[2 * i + 1] & 0xffff0000u) + bq[4 * i + 3];
        hlo0 = hlo0 > 0.f ? hlo0 : 0.f;
        hhi0 = hhi0 > 0.f ? hhi0 : 0.f;
        hlo1 = hlo1 > 0.f ? hlo1 : 0.f;
        hhi1 = hhi1 > 0.f ? hhi1 : 0.f;
        p0 = fmaf(hlo0, wv[4 * i], p0);
        p1 = fmaf(hhi0, wv[4 * i + 1], p1);
        p2 = fmaf(hlo1, wv[4 * i + 2], p2);
        p3 = fmaf(hhi1, wv[4 * i + 3], p3);
      }
      float acc = (p0 + p1) + (p2 + p3);
      acc += __shfl_xor(acc, 1);
      acc += __shfl_xor(acc, 2);
      acc += __shfl_xor(acc, 4);
      acc += __shfl_xor(acc, 8);
      if (ls < m && sub == 0) out[e] = acc;  // raw logit
    }
  }
}

// ---------------- sigmoid pass over logits ----------------
__global__ __launch_bounds__(256)
void sigmoid_kernel(float* __restrict__ out, const float* __restrict__ lb2) {
  int i = blockIdx.x * 256 + threadIdx.x;
  if (i < NEDGES) {
    float lb = lb2[0];
    out[i] = 1.0f / (1.0f + expf(-(out[i] + lb)));
  }
}

extern "C" void kernel_launch(void* const* d_in, const int* in_sizes, int n_in,
                              void* d_out, int out_size, void* d_ws, size_t ws_size,
                              hipStream_t stream) {
  const float* x   = (const float*)d_in[0];
  const int*   ei  = (const int*)d_in[1];
  const float* W0  = (const float*)d_in[2];
  const float* b0  = (const float*)d_in[3];
  const float* W1  = (const float*)d_in[4];
  const float* b1  = (const float*)d_in[5];
  const float* W2  = (const float*)d_in[6];
  const float* b2  = (const float*)d_in[7];
  const float* lw1 = (const float*)d_in[8];
  const float* lb1 = (const float*)d_in[9];
  const float* lw2 = (const float*)d_in[10];
  const float* lb2 = (const float*)d_in[11];
  float* out = (float*)d_out;
  const int* src = ei;
  const int* dst = ei + NEDGES;

  char* ws = (char*)d_ws;
  size_t off = 0;
  auto alloc = [&](size_t bytes) -> void* {
    void* p = ws + off;
    off += (bytes + 255) & ~(size_t)255;
    return p;
  };
  int*   cntD   = (int*)alloc((size_t)NNODES * 4);
  int*   startD = (int*)alloc((size_t)NNODES * 4);
  int*   curD   = (int*)alloc((size_t)NNODES * 4);
  float* dis    = (float*)alloc((size_t)NNODES * 4);
  int*   totD   = (int*)alloc(256);
  int2*  csrPair= (int2*)alloc((size_t)NEDGES * 8);
  unsigned short* P16 = (unsigned short*)alloc((size_t)NNODES * 128 * 2);  // bf16 messages
  float* Q      = (float*)alloc((size_t)NNODES * 128 * 4);
  unsigned short* Abuf = (unsigned short*)alloc((size_t)NNODES * 256 * 2);
  unsigned short* Bbuf = (unsigned short*)alloc((size_t)NNODES * 256 * 2);

  hipMemsetAsync(cntD, 0, (size_t)NNODES * 4, stream);
  hipMemsetAsync(totD, 0, 256, stream);
  count_kernel<<<(NEDGES + 255) / 256, 256, 0, stream>>>(dst, cntD);
  alloc_kernel<<<(NNODES + 255) / 256, 256, 0, stream>>>(cntD, startD, curD, dis, totD);
  fill_kernel<<<(NEDGES + 255) / 256, 256, 0, stream>>>(src, dst, curD, csrPair);

  const int GB = (NNODES + 63) / 64;   // gemm blocks
  const int AB = (NNODES * 64) / 256;  // one wave per node (exact: 25000)

  // GCN layers; messages P in bf16 (halves agg gather traffic)
  gemm_kernel<128, 128, true, false, true><<<GB, 256, 0, stream>>>(x, W0, dis, nullptr, P16);
  agg_kernel<128><<<AB, 256, 0, stream>>>(P16, csrPair, startD, cntD, dis, b0, Q);
  gemm_kernel<128, 128, true, false, true><<<GB, 256, 0, stream>>>(Q, W1, dis, nullptr, P16);
  agg_kernel<128><<<AB, 256, 0, stream>>>(P16, csrPair, startD, cntD, dis, b1, Q);
  gemm_kernel<128, 64, true, false, true><<<GB, 256, 0, stream>>>(Q, W2, dis, nullptr, P16);
  agg_kernel<64><<<AB, 256, 0, stream>>>(P16, csrPair, startD, cntD, dis, b2, Q);  // Q now [N,64]

  // edge MLP split: A = z@lw1[0:64,:] + lb1 ; B = z@lw1[64:128,:]
  gemm_kernel<64, 256, false, true, true><<<GB, 256, 0, stream>>>(Q, lw1, nullptr, lb1, Abuf);
  gemm_kernel<64, 256, false, false, true><<<GB, 256, 0, stream>>>(Q, lw1 + 64 * 256, nullptr, nullptr, Bbuf);

  // per-edge (grouped by dst): resident B[dst] slice, gather A[src], relu-dot lw2 -> logit
  edge_kernel<<<AB, 256, 0, stream>>>(Abuf, Bbuf, csrPair, startD, cntD, lw2, out);
  sigmoid_kernel<<<(NEDGES + 255) / 256, 256, 0, stream>>>(out, lb2);
}

// Round 7
// 685.096 us; speedup vs baseline: 1.7427x; 1.1987x over previous
//
#include <hip/hip_runtime.h>

#define NNODES 100000
#define NEDGES 1600000

typedef __attribute__((ext_vector_type(8))) short bf16x8;
typedef __attribute__((ext_vector_type(4))) float f32x4;

__device__ __forceinline__ unsigned short f2bf(float f) {
  unsigned int u = __float_as_uint(f);
  u = (u + 0x7FFFu + ((u >> 16) & 1u)) >> 16;
  return (unsigned short)u;
}
__device__ __forceinline__ float bf2f(unsigned short h) {
  return __uint_as_float(((unsigned int)h) << 16);
}

// ---------------- CSR build (dst side only) ----------------
__global__ void count_kernel(const int* __restrict__ dst, int* __restrict__ cntD) {
  int e = blockIdx.x * 256 + threadIdx.x;
  if (e < NEDGES) atomicAdd(&cntD[dst[e]], 1);
}

__global__ void alloc_kernel(const int* __restrict__ cntD, int* __restrict__ startD,
                             int* __restrict__ curD, float* __restrict__ dis,
                             int* __restrict__ totD) {
  int v = blockIdx.x * 256 + threadIdx.x;
  if (v < NNODES) {
    int c = cntD[v];
    int s = atomicAdd(totD, c);
    startD[v] = s;
    curD[v] = s;
    dis[v] = rsqrtf((float)(c + 1));  // deg = in-degree + self loop
  }
}

__global__ void fill_kernel(const int* __restrict__ src, const int* __restrict__ dst,
                            int* __restrict__ curD, int2* __restrict__ csrPair) {
  int e = blockIdx.x * 256 + threadIdx.x;
  if (e < NEDGES) {
    int s = src[e], d = dst[e];
    int pd = atomicAdd(&curD[d], 1);
    csrPair[pd] = make_int2(s, e);
  }
}

// ---------------- weight pack: row-major [K,HOUT] fp32 -> MFMA B-frag bf16 ----------------
// Wp[(kc*HOUT + c)*32 + j] = bf16(W[kc*32+j][c]); lane reads 8 contiguous at j=(lane>>4)*8.
template <int K, int HOUT>
__global__ void pack_w_kernel(const float* __restrict__ W, unsigned short* __restrict__ Wp) {
  int idx = blockIdx.x * 256 + threadIdx.x;
  if (idx < K * HOUT) {
    int k = idx / HOUT, c = idx - k * HOUT;
    Wp[((size_t)((k >> 5) * HOUT + c)) * 32 + (k & 31)] = f2bf(W[idx]);
  }
}

// pack lw1 ([128,256]) into fused K=64,HOUT=512 table: cols 0-255 = lw1[0:64,:], 256-511 = lw1[64:128,:]
__global__ void pack_lw1_kernel(const float* __restrict__ lw1, const float* __restrict__ lb1,
                                unsigned short* __restrict__ Wp, float* __restrict__ biasAB) {
  int idx = blockIdx.x * 256 + threadIdx.x;
  if (idx < 64 * 512) {
    int k = idx / 512, c = idx - k * 512;
    float v = (c < 256) ? lw1[k * 256 + c] : lw1[(64 + k) * 256 + (c - 256)];
    Wp[((size_t)((k >> 5) * 512 + c)) * 32 + (k & 31)] = f2bf(v);
  }
  if (idx < 512) biasAB[idx] = (idx < 256) ? lb1[idx] : 0.0f;
}

// ---------------- x fp32 -> split bf16 hi/lo planes ----------------
__global__ void cvt_x_kernel(const float* __restrict__ x, unsigned short* __restrict__ hi,
                             unsigned short* __restrict__ lo) {
  int idx = blockIdx.x * 256 + threadIdx.x;
  if (idx < NNODES * 32) {
    float4 v = ((const float4*)x)[idx];
    ushort4 h, l;
    h.x = f2bf(v.x); l.x = f2bf(v.x - bf2f(h.x));
    h.y = f2bf(v.y); l.y = f2bf(v.y - bf2f(h.y));
    h.z = f2bf(v.z); l.z = f2bf(v.z - bf2f(h.z));
    h.w = f2bf(v.w); l.w = f2bf(v.w - bf2f(h.w));
    ((ushort4*)hi)[idx] = h;
    ((ushort4*)lo)[idx] = l;
  }
}

// ---------------- MFMA GEMM: out[r,:] = bf16(( (Xhi+Xlo)[r,:K] @ W ) *dis | +bias) ----------------
// block = 64 rows (4 waves x 16); wave computes 16 rows x HOUT via 16x16x32 MFMA.
template <int K, int HOUT, bool SCALE, bool BIAS>
__global__ __launch_bounds__(256)
void mgemm_kernel(const unsigned short* __restrict__ Xhi, const unsigned short* __restrict__ Xlo,
                  const unsigned short* __restrict__ Wp, const float* __restrict__ dis,
                  const float* __restrict__ bias, unsigned short* __restrict__ outb) {
  constexpr int KC = K / 32;
  const int tid = threadIdx.x;
  const int wave = tid >> 6;
  const int lane = tid & 63;
  const int lrow = lane & 15;   // A row within tile / B+C col
  const int lsub = lane >> 4;   // k-subslice / C row-group
  const int rowBase = blockIdx.x * 64 + wave * 16;
  int arow = rowBase + lrow;
  if (arow > NNODES - 1) arow = NNODES - 1;
  bf16x8 ahi[KC], alo[KC];
#pragma unroll
  for (int kc = 0; kc < KC; ++kc) {
    ahi[kc] = *(const bf16x8*)&Xhi[(size_t)arow * K + kc * 32 + lsub * 8];
    alo[kc] = *(const bf16x8*)&Xlo[(size_t)arow * K + kc * 32 + lsub * 8];
  }
  int orow[4];
  float dis4[4];
#pragma unroll
  for (int i = 0; i < 4; ++i) {
    orow[i] = rowBase + lsub * 4 + i;
    int rc = orow[i] < NNODES ? orow[i] : NNODES - 1;
    dis4[i] = SCALE ? dis[rc] : 1.0f;
  }
  for (int ct = 0; ct < HOUT / 16; ++ct) {
    int c = ct * 16 + lrow;
    f32x4 acc = {0.f, 0.f, 0.f, 0.f};
#pragma unroll
    for (int kc = 0; kc < KC; ++kc) {
      bf16x8 b = *(const bf16x8*)&Wp[((size_t)(kc * HOUT + c)) * 32 + lsub * 8];
      acc = __builtin_amdgcn_mfma_f32_16x16x32_bf16(ahi[kc], b, acc, 0, 0, 0);
      acc = __builtin_amdgcn_mfma_f32_16x16x32_bf16(alo[kc], b, acc, 0, 0, 0);
    }
    float bb = BIAS ? bias[c] : 0.0f;
#pragma unroll
    for (int i = 0; i < 4; ++i) {
      if (orow[i] < NNODES) {
        float v = acc[i];
        if (SCALE) v *= dis4[i];
        if (BIAS) v += bb;
        outb[(size_t)orow[i] * HOUT + c] = f2bf(v);
      }
    }
  }
}

// ---------------- aggregation: one wave per node, bf16 messages -> split bf16 z ----------------
// z[v] = relu(dis[v] * (P[v] + sum_{u} P[u]) + bias); written as hi/lo bf16 planes
template <int HOUT>
__global__ __launch_bounds__(256)
void agg_kernel(const unsigned short* __restrict__ hws, const int2* __restrict__ csrPair,
                const int* __restrict__ startA, const int* __restrict__ cnt,
                const float* __restrict__ dis, const float* __restrict__ bias,
                unsigned short* __restrict__ outHi, unsigned short* __restrict__ outLo) {
  int gid = blockIdx.x * 256 + threadIdx.x;
  int v = gid >> 6;
  int lane = gid & 63;
  constexpr int PER = HOUT / 64;
  float acc0 = 0.0f, acc1 = 0.0f;
  if constexpr (PER == 2) {
    unsigned int o = *(const unsigned int*)&hws[(size_t)v * HOUT + lane * 2];
    acc0 = __uint_as_float(o << 16);
    acc1 = __uint_as_float(o & 0xffff0000u);
  } else {
    acc0 = bf2f(hws[(size_t)v * HOUT + lane]);
  }
  int s0 = startA[v], c = cnt[v];
  for (int base = 0; base < c; base += 64) {
    int rem = c - base;
    int m = rem < 64 ? rem : 64;
    int idx = 0;
    if (lane < m) idx = csrPair[s0 + base + lane].x;
    int j = 0;
    for (; j + 4 <= m; j += 4) {
      int u0 = __shfl(idx, j);
      int u1 = __shfl(idx, j + 1);
      int u2 = __shfl(idx, j + 2);
      int u3 = __shfl(idx, j + 3);
      if constexpr (PER == 2) {
        unsigned int r0 = *(const unsigned int*)&hws[(size_t)u0 * HOUT + lane * 2];
        unsigned int r1 = *(const unsigned int*)&hws[(size_t)u1 * HOUT + lane * 2];
        unsigned int r2 = *(const unsigned int*)&hws[(size_t)u2 * HOUT + lane * 2];
        unsigned int r3 = *(const unsigned int*)&hws[(size_t)u3 * HOUT + lane * 2];
        acc0 += __uint_as_float(r0 << 16) + __uint_as_float(r1 << 16) +
                __uint_as_float(r2 << 16) + __uint_as_float(r3 << 16);
        acc1 += __uint_as_float(r0 & 0xffff0000u) + __uint_as_float(r1 & 0xffff0000u) +
                __uint_as_float(r2 & 0xffff0000u) + __uint_as_float(r3 & 0xffff0000u);
      } else {
        float r0 = bf2f(hws[(size_t)u0 * HOUT + lane]);
        float r1 = bf2f(hws[(size_t)u1 * HOUT + lane]);
        float r2 = bf2f(hws[(size_t)u2 * HOUT + lane]);
        float r3 = bf2f(hws[(size_t)u3 * HOUT + lane]);
        acc0 += (r0 + r1) + (r2 + r3);
      }
    }
    for (; j < m; ++j) {
      int u = __shfl(idx, j);
      if constexpr (PER == 2) {
        unsigned int r = *(const unsigned int*)&hws[(size_t)u * HOUT + lane * 2];
        acc0 += __uint_as_float(r << 16);
        acc1 += __uint_as_float(r & 0xffff0000u);
      } else {
        acc0 += bf2f(hws[(size_t)u * HOUT + lane]);
      }
    }
  }
  float d = dis[v];
  if constexpr (PER == 2) {
    float o0 = fmaf(d, acc0, bias[lane * 2]);
    float o1 = fmaf(d, acc1, bias[lane * 2 + 1]);
    o0 = o0 > 0.0f ? o0 : 0.0f;
    o1 = o1 > 0.0f ? o1 : 0.0f;
    ushort2 h, l;
    h.x = f2bf(o0); l.x = f2bf(o0 - bf2f(h.x));
    h.y = f2bf(o1); l.y = f2bf(o1 - bf2f(h.y));
    *(ushort2*)&outHi[(size_t)v * HOUT + lane * 2] = h;
    *(ushort2*)&outLo[(size_t)v * HOUT + lane * 2] = l;
  } else {
    float o0 = fmaf(d, acc0, bias[lane]);
    o0 = o0 > 0.0f ? o0 : 0.0f;
    unsigned short h = f2bf(o0);
    outHi[(size_t)v * HOUT + lane] = h;
    outLo[(size_t)v * HOUT + lane] = f2bf(o0 - bf2f(h));
  }
}

// ---------------- edge classifier: one wave per DST node, 16-lane groups ----------------
// AB table: row stride 512; cols 0-255 = A (z@lw1a+lb1), 256-511 = B (z@lw1b)
__global__ __launch_bounds__(256)
void edge_kernel(const unsigned short* __restrict__ AB,
                 const int2* __restrict__ csrPair,
                 const int* __restrict__ startD, const int* __restrict__ cntD,
                 const float* __restrict__ lw2,
                 float* __restrict__ out) {
  int gid = blockIdx.x * 256 + threadIdx.x;
  int v = gid >> 6;
  int lane = gid & 63;
  int sub = lane & 15;   // dim-slice owner within group
  const unsigned int* Brow = (const unsigned int*)&AB[(size_t)v * 512 + 256 + sub * 16];
  uint4 br0 = *(const uint4*)Brow;
  uint4 br1 = *(const uint4*)(Brow + 4);
  float bq[16];
  {
    unsigned int u[8] = {br0.x, br0.y, br0.z, br0.w, br1.x, br1.y, br1.z, br1.w};
#pragma unroll
    for (int i = 0; i < 8; ++i) {
      bq[2 * i]     = __uint_as_float(u[i] << 16);
      bq[2 * i + 1] = __uint_as_float(u[i] & 0xffff0000u);
    }
  }
  float wv[16];
#pragma unroll
  for (int i = 0; i < 4; ++i) {
    float4 w4 = *(const float4*)&lw2[sub * 16 + i * 4];
    wv[4 * i] = w4.x; wv[4 * i + 1] = w4.y; wv[4 * i + 2] = w4.z; wv[4 * i + 3] = w4.w;
  }

  int s0 = startD[v], c = cntD[v];
  for (int base = 0; base < c; base += 64) {
    int rem = c - base;
    int m = rem < 64 ? rem : 64;
    int sj = 0, ej = 0;
    if (lane < m) {
      int2 p = csrPair[s0 + base + lane];
      sj = p.x; ej = p.y;
    }
    for (int j = 0; j < m; j += 4) {
      int ls = j + (lane >> 4);              // group g handles edge j+g
      int lsc = ls < m ? ls : m - 1;         // clamp tail (duplicate row, same lines)
      int s = __shfl(sj, lsc);
      int e = __shfl(ej, lsc);
      const unsigned int* Arow = (const unsigned int*)&AB[(size_t)(unsigned)s * 512 + sub * 16];
      uint4 a0 = *(const uint4*)Arow;
      uint4 a1 = *(const uint4*)(Arow + 4);
      unsigned int au[8] = {a0.x, a0.y, a0.z, a0.w, a1.x, a1.y, a1.z, a1.w};
      float p0 = 0.f, p1 = 0.f, p2 = 0.f, p3 = 0.f;
#pragma unroll
      for (int i = 0; i < 4; ++i) {
        float hlo0 = __uint_as_float(au[2 * i] << 16) + bq[4 * i];
        float hhi0 = __uint_as_float(au[2 * i] & 0xffff0000u) + bq[4 * i + 1];
        float hlo1 = __uint_as_float(au[2 * i + 1] << 16) + bq[4 * i + 2];
        float hhi1 = __uint_as_float(au[2 * i + 1] & 0xffff0000u) + bq[4 * i + 3];
        hlo0 = hlo0 > 0.f ? hlo0 : 0.f;
        hhi0 = hhi0 > 0.f ? hhi0 : 0.f;
        hlo1 = hlo1 > 0.f ? hlo1 : 0.f;
        hhi1 = hhi1 > 0.f ? hhi1 : 0.f;
        p0 = fmaf(hlo0, wv[4 * i], p0);
        p1 = fmaf(hhi0, wv[4 * i + 1], p1);
        p2 = fmaf(hlo1, wv[4 * i + 2], p2);
        p3 = fmaf(hhi1, wv[4 * i + 3], p3);
      }
      float acc = (p0 + p1) + (p2 + p3);
      acc += __shfl_xor(acc, 1);
      acc += __shfl_xor(acc, 2);
      acc += __shfl_xor(acc, 4);
      acc += __shfl_xor(acc, 8);
      if (ls < m && sub == 0) out[e] = acc;  // raw logit
    }
  }
}

// ---------------- sigmoid pass over logits ----------------
__global__ __launch_bounds__(256)
void sigmoid_kernel(float* __restrict__ out, const float* __restrict__ lb2) {
  int i = blockIdx.x * 256 + threadIdx.x;
  if (i < NEDGES) {
    float lb = lb2[0];
    out[i] = 1.0f / (1.0f + expf(-(out[i] + lb)));
  }
}

extern "C" void kernel_launch(void* const* d_in, const int* in_sizes, int n_in,
                              void* d_out, int out_size, void* d_ws, size_t ws_size,
                              hipStream_t stream) {
  const float* x   = (const float*)d_in[0];
  const int*   ei  = (const int*)d_in[1];
  const float* W0  = (const float*)d_in[2];
  const float* b0  = (const float*)d_in[3];
  const float* W1  = (const float*)d_in[4];
  const float* b1  = (const float*)d_in[5];
  const float* W2  = (const float*)d_in[6];
  const float* b2  = (const float*)d_in[7];
  const float* lw1 = (const float*)d_in[8];
  const float* lb1 = (const float*)d_in[9];
  const float* lw2 = (const float*)d_in[10];
  const float* lb2 = (const float*)d_in[11];
  float* out = (float*)d_out;
  const int* src = ei;
  const int* dst = ei + NEDGES;

  char* ws = (char*)d_ws;
  size_t off = 0;
  auto alloc = [&](size_t bytes) -> void* {
    void* p = ws + off;
    off += (bytes + 255) & ~(size_t)255;
    return p;
  };
  int*   cntD   = (int*)alloc((size_t)NNODES * 4);
  int*   startD = (int*)alloc((size_t)NNODES * 4);
  int*   curD   = (int*)alloc((size_t)NNODES * 4);
  float* dis    = (float*)alloc((size_t)NNODES * 4);
  int*   totD   = (int*)alloc(256);
  int2*  csrPair= (int2*)alloc((size_t)NEDGES * 8);
  unsigned short* P16  = (unsigned short*)alloc((size_t)NNODES * 128 * 2);  // bf16 messages
  unsigned short* XQhi = (unsigned short*)alloc((size_t)NNODES * 128 * 2);  // x / z hi plane
  unsigned short* XQlo = (unsigned short*)alloc((size_t)NNODES * 128 * 2);  // x / z lo plane
  unsigned short* AB   = (unsigned short*)alloc((size_t)NNODES * 512 * 2);  // fused A|B tables
  unsigned short* Wp0  = (unsigned short*)alloc((size_t)128 * 128 * 2);
  unsigned short* Wp1  = (unsigned short*)alloc((size_t)128 * 128 * 2);
  unsigned short* Wp2  = (unsigned short*)alloc((size_t)128 * 64 * 2);
  unsigned short* WpE  = (unsigned short*)alloc((size_t)64 * 512 * 2);
  float* biasAB = (float*)alloc(512 * 4);
  // ~193 MB total

  hipMemsetAsync(cntD, 0, (size_t)NNODES * 4, stream);
  hipMemsetAsync(totD, 0, 256, stream);
  count_kernel<<<(NEDGES + 255) / 256, 256, 0, stream>>>(dst, cntD);
  alloc_kernel<<<(NNODES + 255) / 256, 256, 0, stream>>>(cntD, startD, curD, dis, totD);
  fill_kernel<<<(NEDGES + 255) / 256, 256, 0, stream>>>(src, dst, curD, csrPair);

  pack_w_kernel<128, 128><<<64, 256, 0, stream>>>(W0, Wp0);
  pack_w_kernel<128, 128><<<64, 256, 0, stream>>>(W1, Wp1);
  pack_w_kernel<128, 64><<<32, 256, 0, stream>>>(W2, Wp2);
  pack_lw1_kernel<<<128, 256, 0, stream>>>(lw1, lb1, WpE, biasAB);
  cvt_x_kernel<<<(NNODES * 32 + 255) / 256, 256, 0, stream>>>(x, XQhi, XQlo);

  const int GB = (NNODES + 63) / 64;   // mgemm blocks (64 rows each)
  const int AB_ = (NNODES * 64) / 256; // one wave per node (exact: 25000)

  // layer 0..2: P = (z@W)*dis (bf16), z' = relu(dis*agg + b) split into hi/lo planes
  mgemm_kernel<128, 128, true, false><<<GB, 256, 0, stream>>>(XQhi, XQlo, Wp0, dis, nullptr, P16);
  agg_kernel<128><<<AB_, 256, 0, stream>>>(P16, csrPair, startD, cntD, dis, b0, XQhi, XQlo);
  mgemm_kernel<128, 128, true, false><<<GB, 256, 0, stream>>>(XQhi, XQlo, Wp1, dis, nullptr, P16);
  agg_kernel<128><<<AB_, 256, 0, stream>>>(P16, csrPair, startD, cntD, dis, b1, XQhi, XQlo);
  mgemm_kernel<128, 64, true, false><<<GB, 256, 0, stream>>>(XQhi, XQlo, Wp2, dis, nullptr, P16);
  agg_kernel<64><<<AB_, 256, 0, stream>>>(P16, csrPair, startD, cntD, dis, b2, XQhi, XQlo);

  // fused edge-MLP tables: AB[:,0:256] = z@lw1a + lb1 ; AB[:,256:512] = z@lw1b
  mgemm_kernel<64, 512, false, true><<<GB, 256, 0, stream>>>(XQhi, XQlo, WpE, nullptr, biasAB, AB);

  // per-edge (grouped by dst): resident B slice, gather A[src], relu-dot lw2 -> logit
  edge_kernel<<<AB_, 256, 0, stream>>>(AB, csrPair, startD, cntD, lw2, out);
  sigmoid_kernel<<<(NEDGES + 255) / 256, 256, 0, stream>>>(out, lb2);
}

// Round 8
// 615.676 us; speedup vs baseline: 1.9392x; 1.1128x over previous
//
#include <hip/hip_runtime.h>

#define NNODES 100000
#define NEDGES 1600000
#define NBLK 391          // ceil(NNODES/256)
#define NSLICE 8
#define SLICEW 12500      // NNODES / NSLICE (exact)

typedef __attribute__((ext_vector_type(8))) short bf16x8;
typedef __attribute__((ext_vector_type(4))) float f32x4;

__device__ __forceinline__ unsigned short f2bf(float f) {
  unsigned int u = __float_as_uint(f);
  u = (u + 0x7FFFu + ((u >> 16) & 1u)) >> 16;
  return (unsigned short)u;
}
__device__ __forceinline__ float bf2f(unsigned short h) {
  return __uint_as_float(((unsigned int)h) << 16);
}

// ---------------- CSR build: dst-range-sliced count + ordered scan + sliced fill ----------------
// slice = blockIdx&7 -> (round-robin) XCD affinity; each slice's counters/csr region is L2-local.
__global__ void count_kernel(const int* __restrict__ dst, int* __restrict__ cntD) {
  int slice = blockIdx.x & (NSLICE - 1);
  int e = (blockIdx.x >> 3) * 256 + threadIdx.x;
  if (e >= NEDGES) return;
  int d = dst[e];
  int lo = slice * SLICEW;
  if (d >= lo && d < lo + SLICEW) atomicAdd(&cntD[d], 1);
}

// per-block sums of cntD
__global__ void scanA_kernel(const int* __restrict__ cntD, int* __restrict__ blockSum) {
  __shared__ int sh[256];
  int v = blockIdx.x * 256 + threadIdx.x;
  sh[threadIdx.x] = (v < NNODES) ? cntD[v] : 0;
  __syncthreads();
  for (int off = 128; off; off >>= 1) {
    if (threadIdx.x < off) sh[threadIdx.x] += sh[threadIdx.x + off];
    __syncthreads();
  }
  if (threadIdx.x == 0) blockSum[blockIdx.x] = sh[0];
}

// exclusive scan of NBLK block sums; single wave with carry
__global__ void scanB_kernel(int* __restrict__ blockSum) {
  int lane = threadIdx.x;  // 0..63
  int carry = 0;
  for (int base = 0; base < NBLK; base += 64) {
    int i = base + lane;
    int c = (i < NBLK) ? blockSum[i] : 0;
    int pre = c;
#pragma unroll
    for (int off = 1; off < 64; off <<= 1) {
      int t = __shfl_up(pre, off);
      if (lane >= off) pre += t;
    }
    int tot = __shfl(pre, 63);
    if (i < NBLK) blockSum[i] = carry + pre - c;  // exclusive
    carry += tot;
  }
}

// block-local scan + base -> startD/curD/dis (startD monotone in v => compact slice regions)
__global__ void scanC_kernel(const int* __restrict__ cntD, const int* __restrict__ blockSum,
                             int* __restrict__ startD, int* __restrict__ curD,
                             float* __restrict__ dis) {
  __shared__ int sh[256];
  int tid = threadIdx.x;
  int v = blockIdx.x * 256 + tid;
  int c = (v < NNODES) ? cntD[v] : 0;
  sh[tid] = c;
  __syncthreads();
  for (int off = 1; off < 256; off <<= 1) {
    int t = (tid >= off) ? sh[tid - off] : 0;
    __syncthreads();
    sh[tid] += t;
    __syncthreads();
  }
  if (v < NNODES) {
    int s = blockSum[blockIdx.x] + sh[tid] - c;  // exclusive prefix
    startD[v] = s;
    curD[v] = s;
    dis[v] = rsqrtf((float)(c + 1));  // deg = in-degree + self loop
  }
}

__global__ void fill_kernel(const int* __restrict__ src, const int* __restrict__ dst,
                            int* __restrict__ curD, int2* __restrict__ csrPair) {
  int slice = blockIdx.x & (NSLICE - 1);
  int e = (blockIdx.x >> 3) * 256 + threadIdx.x;
  if (e >= NEDGES) return;
  int d = dst[e];
  int lo = slice * SLICEW;
  if (d < lo || d >= lo + SLICEW) return;
  int s = src[e];
  int pd = atomicAdd(&curD[d], 1);
  csrPair[pd] = make_int2(s, e);
}

// ---------------- weight pack: row-major [K,HOUT] fp32 -> MFMA B-frag bf16 ----------------
template <int K, int HOUT>
__global__ void pack_w_kernel(const float* __restrict__ W, unsigned short* __restrict__ Wp) {
  int idx = blockIdx.x * 256 + threadIdx.x;
  if (idx < K * HOUT) {
    int k = idx / HOUT, c = idx - k * HOUT;
    Wp[((size_t)((k >> 5) * HOUT + c)) * 32 + (k & 31)] = f2bf(W[idx]);
  }
}

// pack lw1 ([128,256]) into fused K=64,HOUT=512 table
__global__ void pack_lw1_kernel(const float* __restrict__ lw1, const float* __restrict__ lb1,
                                unsigned short* __restrict__ Wp, float* __restrict__ biasAB) {
  int idx = blockIdx.x * 256 + threadIdx.x;
  if (idx < 64 * 512) {
    int k = idx / 512, c = idx - k * 512;
    float v = (c < 256) ? lw1[k * 256 + c] : lw1[(64 + k) * 256 + (c - 256)];
    Wp[((size_t)((k >> 5) * 512 + c)) * 32 + (k & 31)] = f2bf(v);
  }
  if (idx < 512) biasAB[idx] = (idx < 256) ? lb1[idx] : 0.0f;
}

// ---------------- x fp32 -> split bf16 hi/lo planes ----------------
__global__ void cvt_x_kernel(const float* __restrict__ x, unsigned short* __restrict__ hi,
                             unsigned short* __restrict__ lo) {
  int idx = blockIdx.x * 256 + threadIdx.x;
  if (idx < NNODES * 32) {
    float4 v = ((const float4*)x)[idx];
    ushort4 h, l;
    h.x = f2bf(v.x); l.x = f2bf(v.x - bf2f(h.x));
    h.y = f2bf(v.y); l.y = f2bf(v.y - bf2f(h.y));
    h.z = f2bf(v.z); l.z = f2bf(v.z - bf2f(h.z));
    h.w = f2bf(v.w); l.w = f2bf(v.w - bf2f(h.w));
    ((ushort4*)hi)[idx] = h;
    ((ushort4*)lo)[idx] = l;
  }
}

// ---------------- MFMA GEMM (split-bf16 A, bf16 W) ----------------
template <int K, int HOUT, bool SCALE, bool BIAS>
__global__ __launch_bounds__(256)
void mgemm_kernel(const unsigned short* __restrict__ Xhi, const unsigned short* __restrict__ Xlo,
                  const unsigned short* __restrict__ Wp, const float* __restrict__ dis,
                  const float* __restrict__ bias, unsigned short* __restrict__ outb) {
  constexpr int KC = K / 32;
  const int tid = threadIdx.x;
  const int wave = tid >> 6;
  const int lane = tid & 63;
  const int lrow = lane & 15;
  const int lsub = lane >> 4;
  const int rowBase = blockIdx.x * 64 + wave * 16;
  int arow = rowBase + lrow;
  if (arow > NNODES - 1) arow = NNODES - 1;
  bf16x8 ahi[KC], alo[KC];
#pragma unroll
  for (int kc = 0; kc < KC; ++kc) {
    ahi[kc] = *(const bf16x8*)&Xhi[(size_t)arow * K + kc * 32 + lsub * 8];
    alo[kc] = *(const bf16x8*)&Xlo[(size_t)arow * K + kc * 32 + lsub * 8];
  }
  int orow[4];
  float dis4[4];
#pragma unroll
  for (int i = 0; i < 4; ++i) {
    orow[i] = rowBase + lsub * 4 + i;
    int rc = orow[i] < NNODES ? orow[i] : NNODES - 1;
    dis4[i] = SCALE ? dis[rc] : 1.0f;
  }
  for (int ct = 0; ct < HOUT / 16; ++ct) {
    int c = ct * 16 + lrow;
    f32x4 acc = {0.f, 0.f, 0.f, 0.f};
#pragma unroll
    for (int kc = 0; kc < KC; ++kc) {
      bf16x8 b = *(const bf16x8*)&Wp[((size_t)(kc * HOUT + c)) * 32 + lsub * 8];
      acc = __builtin_amdgcn_mfma_f32_16x16x32_bf16(ahi[kc], b, acc, 0, 0, 0);
      acc = __builtin_amdgcn_mfma_f32_16x16x32_bf16(alo[kc], b, acc, 0, 0, 0);
    }
    float bb = BIAS ? bias[c] : 0.0f;
#pragma unroll
    for (int i = 0; i < 4; ++i) {
      if (orow[i] < NNODES) {
        float v = acc[i];
        if (SCALE) v *= dis4[i];
        if (BIAS) v += bb;
        outb[(size_t)orow[i] * HOUT + c] = f2bf(v);
      }
    }
  }
}

// ---------------- aggregation: one wave per node, bf16 messages -> split bf16 z ----------------
template <int HOUT>
__global__ __launch_bounds__(256)
void agg_kernel(const unsigned short* __restrict__ hws, const int2* __restrict__ csrPair,
                const int* __restrict__ startA, const int* __restrict__ cnt,
                const float* __restrict__ dis, const float* __restrict__ bias,
                unsigned short* __restrict__ outHi, unsigned short* __restrict__ outLo) {
  int gid = blockIdx.x * 256 + threadIdx.x;
  int v = gid >> 6;
  int lane = gid & 63;
  constexpr int PER = HOUT / 64;
  float acc0 = 0.0f, acc1 = 0.0f;
  if constexpr (PER == 2) {
    unsigned int o = *(const unsigned int*)&hws[(size_t)v * HOUT + lane * 2];
    acc0 = __uint_as_float(o << 16);
    acc1 = __uint_as_float(o & 0xffff0000u);
  } else {
    acc0 = bf2f(hws[(size_t)v * HOUT + lane]);
  }
  int s0 = startA[v], c = cnt[v];
  for (int base = 0; base < c; base += 64) {
    int rem = c - base;
    int m = rem < 64 ? rem : 64;
    int idx = 0;
    if (lane < m) idx = csrPair[s0 + base + lane].x;
    int j = 0;
    for (; j + 4 <= m; j += 4) {
      int u0 = __shfl(idx, j);
      int u1 = __shfl(idx, j + 1);
      int u2 = __shfl(idx, j + 2);
      int u3 = __shfl(idx, j + 3);
      if constexpr (PER == 2) {
        unsigned int r0 = *(const unsigned int*)&hws[(size_t)u0 * HOUT + lane * 2];
        unsigned int r1 = *(const unsigned int*)&hws[(size_t)u1 * HOUT + lane * 2];
        unsigned int r2 = *(const unsigned int*)&hws[(size_t)u2 * HOUT + lane * 2];
        unsigned int r3 = *(const unsigned int*)&hws[(size_t)u3 * HOUT + lane * 2];
        acc0 += __uint_as_float(r0 << 16) + __uint_as_float(r1 << 16) +
                __uint_as_float(r2 << 16) + __uint_as_float(r3 << 16);
        acc1 += __uint_as_float(r0 & 0xffff0000u) + __uint_as_float(r1 & 0xffff0000u) +
                __uint_as_float(r2 & 0xffff0000u) + __uint_as_float(r3 & 0xffff0000u);
      } else {
        float r0 = bf2f(hws[(size_t)u0 * HOUT + lane]);
        float r1 = bf2f(hws[(size_t)u1 * HOUT + lane]);
        float r2 = bf2f(hws[(size_t)u2 * HOUT + lane]);
        float r3 = bf2f(hws[(size_t)u3 * HOUT + lane]);
        acc0 += (r0 + r1) + (r2 + r3);
      }
    }
    for (; j < m; ++j) {
      int u = __shfl(idx, j);
      if constexpr (PER == 2) {
        unsigned int r = *(const unsigned int*)&hws[(size_t)u * HOUT + lane * 2];
        acc0 += __uint_as_float(r << 16);
        acc1 += __uint_as_float(r & 0xffff0000u);
      } else {
        acc0 += bf2f(hws[(size_t)u * HOUT + lane]);
      }
    }
  }
  float d = dis[v];
  if constexpr (PER == 2) {
    float o0 = fmaf(d, acc0, bias[lane * 2]);
    float o1 = fmaf(d, acc1, bias[lane * 2 + 1]);
    o0 = o0 > 0.0f ? o0 : 0.0f;
    o1 = o1 > 0.0f ? o1 : 0.0f;
    ushort2 h, l;
    h.x = f2bf(o0); l.x = f2bf(o0 - bf2f(h.x));
    h.y = f2bf(o1); l.y = f2bf(o1 - bf2f(h.y));
    *(ushort2*)&outHi[(size_t)v * HOUT + lane * 2] = h;
    *(ushort2*)&outLo[(size_t)v * HOUT + lane * 2] = l;
  } else {
    float o0 = fmaf(d, acc0, bias[lane]);
    o0 = o0 > 0.0f ? o0 : 0.0f;
    unsigned short h = f2bf(o0);
    outHi[(size_t)v * HOUT + lane] = h;
    outLo[(size_t)v * HOUT + lane] = f2bf(o0 - bf2f(h));
  }
}

// ---------------- edge classifier: one wave per DST node, 16-lane groups ----------------
__global__ __launch_bounds__(256)
void edge_kernel(const unsigned short* __restrict__ AB,
                 const int2* __restrict__ csrPair,
                 const int* __restrict__ startD, const int* __restrict__ cntD,
                 const float* __restrict__ lw2,
                 float* __restrict__ out) {
  int gid = blockIdx.x * 256 + threadIdx.x;
  int v = gid >> 6;
  int lane = gid & 63;
  int sub = lane & 15;
  const unsigned int* Brow = (const unsigned int*)&AB[(size_t)v * 512 + 256 + sub * 16];
  uint4 br0 = *(const uint4*)Brow;
  uint4 br1 = *(const uint4*)(Brow + 4);
  float bq[16];
  {
    unsigned int u[8] = {br0.x, br0.y, br0.z, br0.w, br1.x, br1.y, br1.z, br1.w};
#pragma unroll
    for (int i = 0; i < 8; ++i) {
      bq[2 * i]     = __uint_as_float(u[i] << 16);
      bq[2 * i + 1] = __uint_as_float(u[i] & 0xffff0000u);
    }
  }
  float wv[16];
#pragma unroll
  for (int i = 0; i < 4; ++i) {
    float4 w4 = *(const float4*)&lw2[sub * 16 + i * 4];
    wv[4 * i] = w4.x; wv[4 * i + 1] = w4.y; wv[4 * i + 2] = w4.z; wv[4 * i + 3] = w4.w;
  }

  int s0 = startD[v], c = cntD[v];
  for (int base = 0; base < c; base += 64) {
    int rem = c - base;
    int m = rem < 64 ? rem : 64;
    int sj = 0, ej = 0;
    if (lane < m) {
      int2 p = csrPair[s0 + base + lane];
      sj = p.x; ej = p.y;
    }
    for (int j = 0; j < m; j += 4) {
      int ls = j + (lane >> 4);
      int lsc = ls < m ? ls : m - 1;
      int s = __shfl(sj, lsc);
      int e = __shfl(ej, lsc);
      const unsigned int* Arow = (const unsigned int*)&AB[(size_t)(unsigned)s * 512 + sub * 16];
      uint4 a0 = *(const uint4*)Arow;
      uint4 a1 = *(const uint4*)(Arow + 4);
      unsigned int au[8] = {a0.x, a0.y, a0.z, a0.w, a1.x, a1.y, a1.z, a1.w};
      float p0 = 0.f, p1 = 0.f, p2 = 0.f, p3 = 0.f;
#pragma unroll
      for (int i = 0; i < 4; ++i) {
        float hlo0 = __uint_as_float(au[2 * i] << 16) + bq[4 * i];
        float hhi0 = __uint_as_float(au[2 * i] & 0xffff0000u) + bq[4 * i + 1];
        float hlo1 = __uint_as_float(au[2 * i + 1] << 16) + bq[4 * i + 2];
        float hhi1 = __uint_as_float(au[2 * i + 1] & 0xffff0000u) + bq[4 * i + 3];
        hlo0 = hlo0 > 0.f ? hlo0 : 0.f;
        hhi0 = hhi0 > 0.f ? hhi0 : 0.f;
        hlo1 = hlo1 > 0.f ? hlo1 : 0.f;
        hhi1 = hhi1 > 0.f ? hhi1 : 0.f;
        p0 = fmaf(hlo0, wv[4 * i], p0);
        p1 = fmaf(hhi0, wv[4 * i + 1], p1);
        p2 = fmaf(hlo1, wv[4 * i + 2], p2);
        p3 = fmaf(hhi1, wv[4 * i + 3], p3);
      }
      float acc = (p0 + p1) + (p2 + p3);
      acc += __shfl_xor(acc, 1);
      acc += __shfl_xor(acc, 2);
      acc += __shfl_xor(acc, 4);
      acc += __shfl_xor(acc, 8);
      if (ls < m && sub == 0) out[e] = acc;
    }
  }
}

// ---------------- sigmoid pass over logits ----------------
__global__ __launch_bounds__(256)
void sigmoid_kernel(float* __restrict__ out, const float* __restrict__ lb2) {
  int i = blockIdx.x * 256 + threadIdx.x;
  if (i < NEDGES) {
    float lb = lb2[0];
    out[i] = 1.0f / (1.0f + expf(-(out[i] + lb)));
  }
}

extern "C" void kernel_launch(void* const* d_in, const int* in_sizes, int n_in,
                              void* d_out, int out_size, void* d_ws, size_t ws_size,
                              hipStream_t stream) {
  const float* x   = (const float*)d_in[0];
  const int*   ei  = (const int*)d_in[1];
  const float* W0  = (const float*)d_in[2];
  const float* b0  = (const float*)d_in[3];
  const float* W1  = (const float*)d_in[4];
  const float* b1  = (const float*)d_in[5];
  const float* W2  = (const float*)d_in[6];
  const float* b2  = (const float*)d_in[7];
  const float* lw1 = (const float*)d_in[8];
  const float* lb1 = (const float*)d_in[9];
  const float* lw2 = (const float*)d_in[10];
  const float* lb2 = (const float*)d_in[11];
  float* out = (float*)d_out;
  const int* src = ei;
  const int* dst = ei + NEDGES;

  char* ws = (char*)d_ws;
  size_t off = 0;
  auto alloc = [&](size_t bytes) -> void* {
    void* p = ws + off;
    off += (bytes + 255) & ~(size_t)255;
    return p;
  };
  int*   cntD   = (int*)alloc((size_t)NNODES * 4);
  int*   startD = (int*)alloc((size_t)NNODES * 4);
  int*   curD   = (int*)alloc((size_t)NNODES * 4);
  float* dis    = (float*)alloc((size_t)NNODES * 4);
  int*   blockSum = (int*)alloc((size_t)NBLK * 4);
  int2*  csrPair= (int2*)alloc((size_t)NEDGES * 8);
  unsigned short* P16  = (unsigned short*)alloc((size_t)NNODES * 128 * 2);
  unsigned short* XQhi = (unsigned short*)alloc((size_t)NNODES * 128 * 2);
  unsigned short* XQlo = (unsigned short*)alloc((size_t)NNODES * 128 * 2);
  unsigned short* AB   = (unsigned short*)alloc((size_t)NNODES * 512 * 2);
  unsigned short* Wp0  = (unsigned short*)alloc((size_t)128 * 128 * 2);
  unsigned short* Wp1  = (unsigned short*)alloc((size_t)128 * 128 * 2);
  unsigned short* Wp2  = (unsigned short*)alloc((size_t)128 * 64 * 2);
  unsigned short* WpE  = (unsigned short*)alloc((size_t)64 * 512 * 2);
  float* biasAB = (float*)alloc(512 * 4);

  const int EB8 = NSLICE * ((NEDGES + 255) / 256);  // sliced edge-scan grid

  hipMemsetAsync(cntD, 0, (size_t)NNODES * 4, stream);
  count_kernel<<<EB8, 256, 0, stream>>>(dst, cntD);
  scanA_kernel<<<NBLK, 256, 0, stream>>>(cntD, blockSum);
  scanB_kernel<<<1, 64, 0, stream>>>(blockSum);
  scanC_kernel<<<NBLK, 256, 0, stream>>>(cntD, blockSum, startD, curD, dis);
  fill_kernel<<<EB8, 256, 0, stream>>>(src, dst, curD, csrPair);

  pack_w_kernel<128, 128><<<64, 256, 0, stream>>>(W0, Wp0);
  pack_w_kernel<128, 128><<<64, 256, 0, stream>>>(W1, Wp1);
  pack_w_kernel<128, 64><<<32, 256, 0, stream>>>(W2, Wp2);
  pack_lw1_kernel<<<128, 256, 0, stream>>>(lw1, lb1, WpE, biasAB);
  cvt_x_kernel<<<(NNODES * 32 + 255) / 256, 256, 0, stream>>>(x, XQhi, XQlo);

  const int GB = (NNODES + 63) / 64;
  const int AB_ = (NNODES * 64) / 256;

  mgemm_kernel<128, 128, true, false><<<GB, 256, 0, stream>>>(XQhi, XQlo, Wp0, dis, nullptr, P16);
  agg_kernel<128><<<AB_, 256, 0, stream>>>(P16, csrPair, startD, cntD, dis, b0, XQhi, XQlo);
  mgemm_kernel<128, 128, true, false><<<GB, 256, 0, stream>>>(XQhi, XQlo, Wp1, dis, nullptr, P16);
  agg_kernel<128><<<AB_, 256, 0, stream>>>(P16, csrPair, startD, cntD, dis, b1, XQhi, XQlo);
  mgemm_kernel<128, 64, true, false><<<GB, 256, 0, stream>>>(XQhi, XQlo, Wp2, dis, nullptr, P16);
  agg_kernel<64><<<AB_, 256, 0, stream>>>(P16, csrPair, startD, cntD, dis, b2, XQhi, XQlo);

  mgemm_kernel<64, 512, false, true><<<GB, 256, 0, stream>>>(XQhi, XQlo, WpE, nullptr, biasAB, AB);

  edge_kernel<<<AB_, 256, 0, stream>>>(AB, csrPair, startD, cntD, lw2, out);
  sigmoid_kernel<<<(NEDGES + 255) / 256, 256, 0, stream>>>(out, lb2);
}

// Round 9
// 594.751 us; speedup vs baseline: 2.0074x; 1.0352x over previous
//
#include <hip/hip_runtime.h>

#define NNODES 100000
#define NEDGES 1600000
#define NBLK 391          // ceil(NNODES/256)
#define NSLICE 8
#define SLICEW 12500      // NNODES / NSLICE (exact)

typedef __attribute__((ext_vector_type(8))) short bf16x8;
typedef __attribute__((ext_vector_type(4))) float f32x4;

__device__ __forceinline__ unsigned short f2bf(float f) {
  unsigned int u = __float_as_uint(f);
  u = (u + 0x7FFFu + ((u >> 16) & 1u)) >> 16;
  return (unsigned short)u;
}
__device__ __forceinline__ float bf2f(unsigned short h) {
  return __uint_as_float(((unsigned int)h) << 16);
}

// packed fp16 helpers (uint carries 2 x f16)
__device__ __forceinline__ unsigned int pk_add_f16(unsigned int a, unsigned int b) {
  unsigned int r;
  asm("v_pk_add_f16 %0, %1, %2" : "=v"(r) : "v"(a), "v"(b));
  return r;
}
__device__ __forceinline__ unsigned int pk_max0_f16(unsigned int a, unsigned int z) {
  unsigned int r;
  asm("v_pk_max_f16 %0, %1, %2" : "=v"(r) : "v"(a), "v"(z));
  return r;
}
__device__ __forceinline__ float dot2_f16(unsigned int a, unsigned int b, float c) {
  float r;
  asm("v_dot2_f32_f16 %0, %1, %2, %3" : "=v"(r) : "v"(a), "v"(b), "v"(c));
  return r;
}

// ---------------- CSR build: dst-range-sliced count + ordered scan + sliced fill ----------------
__global__ void count_kernel(const int* __restrict__ dst, int* __restrict__ cntD) {
  int slice = blockIdx.x & (NSLICE - 1);
  int e = (blockIdx.x >> 3) * 256 + threadIdx.x;
  if (e >= NEDGES) return;
  int d = dst[e];
  int lo = slice * SLICEW;
  if (d >= lo && d < lo + SLICEW) atomicAdd(&cntD[d], 1);
}

__global__ void scanA_kernel(const int* __restrict__ cntD, int* __restrict__ blockSum) {
  __shared__ int sh[256];
  int v = blockIdx.x * 256 + threadIdx.x;
  sh[threadIdx.x] = (v < NNODES) ? cntD[v] : 0;
  __syncthreads();
  for (int off = 128; off; off >>= 1) {
    if (threadIdx.x < off) sh[threadIdx.x] += sh[threadIdx.x + off];
    __syncthreads();
  }
  if (threadIdx.x == 0) blockSum[blockIdx.x] = sh[0];
}

__global__ void scanB_kernel(int* __restrict__ blockSum) {
  int lane = threadIdx.x;  // 0..63
  int carry = 0;
  for (int base = 0; base < NBLK; base += 64) {
    int i = base + lane;
    int c = (i < NBLK) ? blockSum[i] : 0;
    int pre = c;
#pragma unroll
    for (int off = 1; off < 64; off <<= 1) {
      int t = __shfl_up(pre, off);
      if (lane >= off) pre += t;
    }
    int tot = __shfl(pre, 63);
    if (i < NBLK) blockSum[i] = carry + pre - c;  // exclusive
    carry += tot;
  }
}

__global__ void scanC_kernel(const int* __restrict__ cntD, const int* __restrict__ blockSum,
                             int* __restrict__ startD, int* __restrict__ curD,
                             float* __restrict__ dis) {
  __shared__ int sh[256];
  int tid = threadIdx.x;
  int v = blockIdx.x * 256 + tid;
  int c = (v < NNODES) ? cntD[v] : 0;
  sh[tid] = c;
  __syncthreads();
  for (int off = 1; off < 256; off <<= 1) {
    int t = (tid >= off) ? sh[tid - off] : 0;
    __syncthreads();
    sh[tid] += t;
    __syncthreads();
  }
  if (v < NNODES) {
    int s = blockSum[blockIdx.x] + sh[tid] - c;  // exclusive prefix
    startD[v] = s;
    curD[v] = s;
    dis[v] = rsqrtf((float)(c + 1));  // deg = in-degree + self loop
  }
}

__global__ void fill_kernel(const int* __restrict__ src, const int* __restrict__ dst,
                            int* __restrict__ curD, int2* __restrict__ csrPair) {
  int slice = blockIdx.x & (NSLICE - 1);
  int e = (blockIdx.x >> 3) * 256 + threadIdx.x;
  if (e >= NEDGES) return;
  int d = dst[e];
  int lo = slice * SLICEW;
  if (d < lo || d >= lo + SLICEW) return;
  int s = src[e];
  int pd = atomicAdd(&curD[d], 1);
  csrPair[pd] = make_int2(s, e);
}

// ---------------- weight pack: row-major [K,HOUT] fp32 -> MFMA B-frag bf16 ----------------
template <int K, int HOUT>
__global__ void pack_w_kernel(const float* __restrict__ W, unsigned short* __restrict__ Wp) {
  int idx = blockIdx.x * 256 + threadIdx.x;
  if (idx < K * HOUT) {
    int k = idx / HOUT, c = idx - k * HOUT;
    Wp[((size_t)((k >> 5) * HOUT + c)) * 32 + (k & 31)] = f2bf(W[idx]);
  }
}

// pack lw1 into fused K=64,HOUT=512 table; also pack lw2 into fp16 pairs
__global__ void pack_lw1_kernel(const float* __restrict__ lw1, const float* __restrict__ lb1,
                                const float* __restrict__ lw2,
                                unsigned short* __restrict__ Wp, float* __restrict__ biasAB,
                                unsigned int* __restrict__ wh) {
  int idx = blockIdx.x * 256 + threadIdx.x;
  if (idx < 64 * 512) {
    int k = idx / 512, c = idx - k * 512;
    float v = (c < 256) ? lw1[k * 256 + c] : lw1[(64 + k) * 256 + (c - 256)];
    Wp[((size_t)((k >> 5) * 512 + c)) * 32 + (k & 31)] = f2bf(v);
  }
  if (idx < 512) biasAB[idx] = (idx < 256) ? lb1[idx] : 0.0f;
  if (idx < 128) {
    _Float16 lo = (_Float16)lw2[idx * 2];
    _Float16 hi = (_Float16)lw2[idx * 2 + 1];
    unsigned short ulo = __builtin_bit_cast(unsigned short, lo);
    unsigned short uhi = __builtin_bit_cast(unsigned short, hi);
    wh[idx] = (unsigned int)ulo | ((unsigned int)uhi << 16);
  }
}

// ---------------- MFMA GEMM (split-bf16 A, bf16 W) ----------------
// F32IN: read fp32 X and split to hi/lo in registers (layer 0). F16OUT: store fp16 (AB table).
template <int K, int HOUT, bool SCALE, bool BIAS, bool F32IN, bool F16OUT>
__global__ __launch_bounds__(256)
void mgemm_kernel(const void* __restrict__ Xhi_v, const void* __restrict__ Xlo_v,
                  const unsigned short* __restrict__ Wp, const float* __restrict__ dis,
                  const float* __restrict__ bias, void* __restrict__ outv) {
  constexpr int KC = K / 32;
  const int tid = threadIdx.x;
  const int wave = tid >> 6;
  const int lane = tid & 63;
  const int lrow = lane & 15;
  const int lsub = lane >> 4;
  const int rowBase = blockIdx.x * 64 + wave * 16;
  int arow = rowBase + lrow;
  if (arow > NNODES - 1) arow = NNODES - 1;
  bf16x8 ahi[KC], alo[KC];
  if constexpr (F32IN) {
    const float* xf = (const float*)Xhi_v;
#pragma unroll
    for (int kc = 0; kc < KC; ++kc) {
      float4 v0 = *(const float4*)&xf[(size_t)arow * K + kc * 32 + lsub * 8];
      float4 v1 = *(const float4*)&xf[(size_t)arow * K + kc * 32 + lsub * 8 + 4];
      float fv[8] = {v0.x, v0.y, v0.z, v0.w, v1.x, v1.y, v1.z, v1.w};
#pragma unroll
      for (int i = 0; i < 8; ++i) {
        unsigned short h = f2bf(fv[i]);
        ahi[kc][i] = (short)h;
        alo[kc][i] = (short)f2bf(fv[i] - bf2f(h));
      }
    }
  } else {
    const unsigned short* Xhi = (const unsigned short*)Xhi_v;
    const unsigned short* Xlo = (const unsigned short*)Xlo_v;
#pragma unroll
    for (int kc = 0; kc < KC; ++kc) {
      ahi[kc] = *(const bf16x8*)&Xhi[(size_t)arow * K + kc * 32 + lsub * 8];
      alo[kc] = *(const bf16x8*)&Xlo[(size_t)arow * K + kc * 32 + lsub * 8];
    }
  }
  int orow[4];
  float dis4[4];
#pragma unroll
  for (int i = 0; i < 4; ++i) {
    orow[i] = rowBase + lsub * 4 + i;
    int rc = orow[i] < NNODES ? orow[i] : NNODES - 1;
    dis4[i] = SCALE ? dis[rc] : 1.0f;
  }
  for (int ct = 0; ct < HOUT / 16; ++ct) {
    int c = ct * 16 + lrow;
    f32x4 acc = {0.f, 0.f, 0.f, 0.f};
#pragma unroll
    for (int kc = 0; kc < KC; ++kc) {
      bf16x8 b = *(const bf16x8*)&Wp[((size_t)(kc * HOUT + c)) * 32 + lsub * 8];
      acc = __builtin_amdgcn_mfma_f32_16x16x32_bf16(ahi[kc], b, acc, 0, 0, 0);
      acc = __builtin_amdgcn_mfma_f32_16x16x32_bf16(alo[kc], b, acc, 0, 0, 0);
    }
    float bb = BIAS ? bias[c] : 0.0f;
#pragma unroll
    for (int i = 0; i < 4; ++i) {
      if (orow[i] < NNODES) {
        float v = acc[i];
        if (SCALE) v *= dis4[i];
        if (BIAS) v += bb;
        if constexpr (F16OUT) {
          ((_Float16*)outv)[(size_t)orow[i] * HOUT + c] = (_Float16)v;
        } else {
          ((unsigned short*)outv)[(size_t)orow[i] * HOUT + c] = f2bf(v);
        }
      }
    }
  }
}

// ---------------- aggregation: one wave per node, bf16 messages -> split bf16 z ----------------
template <int HOUT>
__global__ __launch_bounds__(256)
void agg_kernel(const unsigned short* __restrict__ hws, const int2* __restrict__ csrPair,
                const int* __restrict__ startA, const int* __restrict__ cnt,
                const float* __restrict__ dis, const float* __restrict__ bias,
                unsigned short* __restrict__ outHi, unsigned short* __restrict__ outLo) {
  int gid = blockIdx.x * 256 + threadIdx.x;
  int v = gid >> 6;
  int lane = gid & 63;
  constexpr int PER = HOUT / 64;
  float acc0 = 0.0f, acc1 = 0.0f;
  if constexpr (PER == 2) {
    unsigned int o = *(const unsigned int*)&hws[(size_t)v * HOUT + lane * 2];
    acc0 = __uint_as_float(o << 16);
    acc1 = __uint_as_float(o & 0xffff0000u);
  } else {
    acc0 = bf2f(hws[(size_t)v * HOUT + lane]);
  }
  int s0 = startA[v], c = cnt[v];
  for (int base = 0; base < c; base += 64) {
    int rem = c - base;
    int m = rem < 64 ? rem : 64;
    int idx = 0;
    if (lane < m) idx = csrPair[s0 + base + lane].x;
    int j = 0;
    for (; j + 4 <= m; j += 4) {
      int u0 = __shfl(idx, j);
      int u1 = __shfl(idx, j + 1);
      int u2 = __shfl(idx, j + 2);
      int u3 = __shfl(idx, j + 3);
      if constexpr (PER == 2) {
        unsigned int r0 = *(const unsigned int*)&hws[(size_t)u0 * HOUT + lane * 2];
        unsigned int r1 = *(const unsigned int*)&hws[(size_t)u1 * HOUT + lane * 2];
        unsigned int r2 = *(const unsigned int*)&hws[(size_t)u2 * HOUT + lane * 2];
        unsigned int r3 = *(const unsigned int*)&hws[(size_t)u3 * HOUT + lane * 2];
        acc0 += __uint_as_float(r0 << 16) + __uint_as_float(r1 << 16) +
                __uint_as_float(r2 << 16) + __uint_as_float(r3 << 16);
        acc1 += __uint_as_float(r0 & 0xffff0000u) + __uint_as_float(r1 & 0xffff0000u) +
                __uint_as_float(r2 & 0xffff0000u) + __uint_as_float(r3 & 0xffff0000u);
      } else {
        float r0 = bf2f(hws[(size_t)u0 * HOUT + lane]);
        float r1 = bf2f(hws[(size_t)u1 * HOUT + lane]);
        float r2 = bf2f(hws[(size_t)u2 * HOUT + lane]);
        float r3 = bf2f(hws[(size_t)u3 * HOUT + lane]);
        acc0 += (r0 + r1) + (r2 + r3);
      }
    }
    for (; j < m; ++j) {
      int u = __shfl(idx, j);
      if constexpr (PER == 2) {
        unsigned int r = *(const unsigned int*)&hws[(size_t)u * HOUT + lane * 2];
        acc0 += __uint_as_float(r << 16);
        acc1 += __uint_as_float(r & 0xffff0000u);
      } else {
        acc0 += bf2f(hws[(size_t)u * HOUT + lane]);
      }
    }
  }
  float d = dis[v];
  if constexpr (PER == 2) {
    float o0 = fmaf(d, acc0, bias[lane * 2]);
    float o1 = fmaf(d, acc1, bias[lane * 2 + 1]);
    o0 = o0 > 0.0f ? o0 : 0.0f;
    o1 = o1 > 0.0f ? o1 : 0.0f;
    ushort2 h, l;
    h.x = f2bf(o0); l.x = f2bf(o0 - bf2f(h.x));
    h.y = f2bf(o1); l.y = f2bf(o1 - bf2f(h.y));
    *(ushort2*)&outHi[(size_t)v * HOUT + lane * 2] = h;
    *(ushort2*)&outLo[(size_t)v * HOUT + lane * 2] = l;
  } else {
    float o0 = fmaf(d, acc0, bias[lane]);
    o0 = o0 > 0.0f ? o0 : 0.0f;
    unsigned short h = f2bf(o0);
    outHi[(size_t)v * HOUT + lane] = h;
    outLo[(size_t)v * HOUT + lane] = f2bf(o0 - bf2f(h));
  }
}

// ---------------- edge classifier: one wave per DST node, 16-lane groups, fp16 packed ----------------
// AB fp16 table: row stride 512; cols 0-255 = A (z@lw1a+lb1), 256-511 = B (z@lw1b)
// 8 edges per iteration (2 batches of 4); sigmoid fused at store.
__global__ __launch_bounds__(256)
void edge_kernel(const unsigned int* __restrict__ AB32,
                 const int2* __restrict__ csrPair,
                 const int* __restrict__ startD, const int* __restrict__ cntD,
                 const unsigned int* __restrict__ wh, const float* __restrict__ lb2,
                 float* __restrict__ out) {
  int gid = blockIdx.x * 256 + threadIdx.x;
  int v = gid >> 6;
  int lane = gid & 63;
  int sub = lane & 15;
  unsigned int zero = 0u;
  // resident B slice (16 dims fp16 = 8 uints) and lw2 slice
  unsigned int bu[8], wu[8];
  {
    const unsigned int* Brow = AB32 + (size_t)v * 256 + 128 + sub * 8;
    uint4 b0 = *(const uint4*)Brow;
    uint4 b1 = *(const uint4*)(Brow + 4);
    bu[0] = b0.x; bu[1] = b0.y; bu[2] = b0.z; bu[3] = b0.w;
    bu[4] = b1.x; bu[5] = b1.y; bu[6] = b1.z; bu[7] = b1.w;
    const unsigned int* W = wh + sub * 8;
    uint4 w0 = *(const uint4*)W;
    uint4 w1 = *(const uint4*)(W + 4);
    wu[0] = w0.x; wu[1] = w0.y; wu[2] = w0.z; wu[3] = w0.w;
    wu[4] = w1.x; wu[5] = w1.y; wu[6] = w1.z; wu[7] = w1.w;
  }
  float lb = lb2[0];

  int s0 = startD[v], c = cntD[v];
  for (int base = 0; base < c; base += 64) {
    int rem = c - base;
    int m = rem < 64 ? rem : 64;
    int sj = 0, ej = 0;
    if (lane < m) {
      int2 p = csrPair[s0 + base + lane];
      sj = p.x; ej = p.y;
    }
    int g = lane >> 4;
    for (int j = 0; j < m; j += 8) {
      int ls0 = j + g, ls1 = j + 4 + g;
      int l0 = ls0 < m ? ls0 : m - 1;
      int l1 = ls1 < m ? ls1 : m - 1;
      int sA = __shfl(sj, l0);
      int eA = __shfl(ej, l0);
      int sB = __shfl(sj, l1);
      int eB = __shfl(ej, l1);
      // issue both A-row loads up front (MLP)
      const unsigned int* ArowA = AB32 + (size_t)(unsigned)sA * 256 + sub * 8;
      const unsigned int* ArowB = AB32 + (size_t)(unsigned)sB * 256 + sub * 8;
      uint4 a00 = *(const uint4*)ArowA;
      uint4 a01 = *(const uint4*)(ArowA + 4);
      uint4 a10 = *(const uint4*)ArowB;
      uint4 a11 = *(const uint4*)(ArowB + 4);
      unsigned int au0[8] = {a00.x, a00.y, a00.z, a00.w, a01.x, a01.y, a01.z, a01.w};
      unsigned int au1[8] = {a10.x, a10.y, a10.z, a10.w, a11.x, a11.y, a11.z, a11.w};
      float acc0 = 0.f, acc1 = 0.f;
#pragma unroll
      for (int i = 0; i < 8; ++i) {
        unsigned int h0 = pk_max0_f16(pk_add_f16(au0[i], bu[i]), zero);
        acc0 = dot2_f16(h0, wu[i], acc0);
        unsigned int h1 = pk_max0_f16(pk_add_f16(au1[i], bu[i]), zero);
        acc1 = dot2_f16(h1, wu[i], acc1);
      }
      acc0 += __shfl_xor(acc0, 1);
      acc0 += __shfl_xor(acc0, 2);
      acc0 += __shfl_xor(acc0, 4);
      acc0 += __shfl_xor(acc0, 8);
      acc1 += __shfl_xor(acc1, 1);
      acc1 += __shfl_xor(acc1, 2);
      acc1 += __shfl_xor(acc1, 4);
      acc1 += __shfl_xor(acc1, 8);
      if (ls0 < m && sub == 0) out[eA] = 1.0f / (1.0f + expf(-(acc0 + lb)));
      if (ls1 < m && sub == 0) out[eB] = 1.0f / (1.0f + expf(-(acc1 + lb)));
    }
  }
}

extern "C" void kernel_launch(void* const* d_in, const int* in_sizes, int n_in,
                              void* d_out, int out_size, void* d_ws, size_t ws_size,
                              hipStream_t stream) {
  const float* x   = (const float*)d_in[0];
  const int*   ei  = (const int*)d_in[1];
  const float* W0  = (const float*)d_in[2];
  const float* b0  = (const float*)d_in[3];
  const float* W1  = (const float*)d_in[4];
  const float* b1  = (const float*)d_in[5];
  const float* W2  = (const float*)d_in[6];
  const float* b2  = (const float*)d_in[7];
  const float* lw1 = (const float*)d_in[8];
  const float* lb1 = (const float*)d_in[9];
  const float* lw2 = (const float*)d_in[10];
  const float* lb2 = (const float*)d_in[11];
  float* out = (float*)d_out;
  const int* src = ei;
  const int* dst = ei + NEDGES;

  char* ws = (char*)d_ws;
  size_t off = 0;
  auto alloc = [&](size_t bytes) -> void* {
    void* p = ws + off;
    off += (bytes + 255) & ~(size_t)255;
    return p;
  };
  int*   cntD   = (int*)alloc((size_t)NNODES * 4);
  int*   startD = (int*)alloc((size_t)NNODES * 4);
  int*   curD   = (int*)alloc((size_t)NNODES * 4);
  float* dis    = (float*)alloc((size_t)NNODES * 4);
  int*   blockSum = (int*)alloc((size_t)NBLK * 4);
  int2*  csrPair= (int2*)alloc((size_t)NEDGES * 8);
  unsigned short* P16  = (unsigned short*)alloc((size_t)NNODES * 128 * 2);
  unsigned short* XQhi = (unsigned short*)alloc((size_t)NNODES * 128 * 2);
  unsigned short* XQlo = (unsigned short*)alloc((size_t)NNODES * 128 * 2);
  void*           AB   = alloc((size_t)NNODES * 512 * 2);   // fp16 A|B tables
  unsigned short* Wp0  = (unsigned short*)alloc((size_t)128 * 128 * 2);
  unsigned short* Wp1  = (unsigned short*)alloc((size_t)128 * 128 * 2);
  unsigned short* Wp2  = (unsigned short*)alloc((size_t)128 * 64 * 2);
  unsigned short* WpE  = (unsigned short*)alloc((size_t)64 * 512 * 2);
  float* biasAB = (float*)alloc(512 * 4);
  unsigned int* wh = (unsigned int*)alloc(128 * 4);

  const int EB8 = NSLICE * ((NEDGES + 255) / 256);

  hipMemsetAsync(cntD, 0, (size_t)NNODES * 4, stream);
  count_kernel<<<EB8, 256, 0, stream>>>(dst, cntD);
  scanA_kernel<<<NBLK, 256, 0, stream>>>(cntD, blockSum);
  scanB_kernel<<<1, 64, 0, stream>>>(blockSum);
  scanC_kernel<<<NBLK, 256, 0, stream>>>(cntD, blockSum, startD, curD, dis);
  fill_kernel<<<EB8, 256, 0, stream>>>(src, dst, curD, csrPair);

  pack_w_kernel<128, 128><<<64, 256, 0, stream>>>(W0, Wp0);
  pack_w_kernel<128, 128><<<64, 256, 0, stream>>>(W1, Wp1);
  pack_w_kernel<128, 64><<<32, 256, 0, stream>>>(W2, Wp2);
  pack_lw1_kernel<<<128, 256, 0, stream>>>(lw1, lb1, lw2, WpE, biasAB, wh);

  const int GB = (NNODES + 63) / 64;
  const int AB_ = (NNODES * 64) / 256;

  // layer 0 reads f32 x directly (cvt fused); layers 1-2 read split-bf16 z planes
  mgemm_kernel<128, 128, true, false, true, false><<<GB, 256, 0, stream>>>(x, nullptr, Wp0, dis, nullptr, P16);
  agg_kernel<128><<<AB_, 256, 0, stream>>>(P16, csrPair, startD, cntD, dis, b0, XQhi, XQlo);
  mgemm_kernel<128, 128, true, false, false, false><<<GB, 256, 0, stream>>>(XQhi, XQlo, Wp1, dis, nullptr, P16);
  agg_kernel<128><<<AB_, 256, 0, stream>>>(P16, csrPair, startD, cntD, dis, b1, XQhi, XQlo);
  mgemm_kernel<128, 64, true, false, false, false><<<GB, 256, 0, stream>>>(XQhi, XQlo, Wp2, dis, nullptr, P16);
  agg_kernel<64><<<AB_, 256, 0, stream>>>(P16, csrPair, startD, cntD, dis, b2, XQhi, XQlo);

  // fused edge-MLP tables in fp16: AB[:,0:256] = z@lw1a + lb1 ; AB[:,256:512] = z@lw1b
  mgemm_kernel<64, 512, false, true, false, true><<<GB, 256, 0, stream>>>(XQhi, XQlo, WpE, nullptr, biasAB, AB);

  // per-edge: resident B slice, gather A[src], packed-f16 relu-dot, fused sigmoid
  edge_kernel<<<AB_, 256, 0, stream>>>((const unsigned int*)AB, csrPair, startD, cntD, wh, lb2, out);
}

// Round 10
// 580.827 us; speedup vs baseline: 2.0556x; 1.0240x over previous
//
#include <hip/hip_runtime.h>

#define NNODES 100000
#define NEDGES 1600000
#define NBLK 391          // ceil(NNODES/256)
#define NSLICE 8
#define SLICEW 12500      // NNODES / NSLICE (exact)
#define CNTB 6250         // NEDGES/256 (exact)
#define GB0 1563          // ceil(NNODES/64) mgemm blocks

typedef __attribute__((ext_vector_type(8))) short bf16x8;
typedef __attribute__((ext_vector_type(4))) float f32x4;

__device__ __forceinline__ unsigned short f2bf(float f) {
  unsigned int u = __float_as_uint(f);
  u = (u + 0x7FFFu + ((u >> 16) & 1u)) >> 16;
  return (unsigned short)u;
}
__device__ __forceinline__ float bf2f(unsigned short h) {
  return __uint_as_float(((unsigned int)h) << 16);
}

// packed fp16 helpers
__device__ __forceinline__ unsigned int pk_add_f16(unsigned int a, unsigned int b) {
  unsigned int r;
  asm("v_pk_add_f16 %0, %1, %2" : "=v"(r) : "v"(a), "v"(b));
  return r;
}
__device__ __forceinline__ unsigned int pk_max0_f16(unsigned int a, unsigned int z) {
  unsigned int r;
  asm("v_pk_max_f16 %0, %1, %2" : "=v"(r) : "v"(a), "v"(z));
  return r;
}
__device__ __forceinline__ float dot2_f16(unsigned int a, unsigned int b, float c) {
  float r;
  asm("v_dot2_f32_f16 %0, %1, %2, %3" : "=v"(r) : "v"(a), "v"(b), "v"(c));
  return r;
}

// ---------------- K1: count (unsliced) ∥ weight packs ----------------
__global__ __launch_bounds__(256)
void k1_kernel(const int* __restrict__ dst, int* __restrict__ cntD,
               const float* __restrict__ W0, const float* __restrict__ W1,
               const float* __restrict__ W2, const float* __restrict__ lw1,
               const float* __restrict__ lb1, const float* __restrict__ lw2,
               unsigned short* __restrict__ Wp0, unsigned short* __restrict__ Wp1,
               unsigned short* __restrict__ Wp2, unsigned short* __restrict__ WpE,
               float* __restrict__ biasAB, unsigned int* __restrict__ wh) {
  int b = blockIdx.x;
  int tid = threadIdx.x;
  if (b < CNTB) {
    int e = b * 256 + tid;
    if (e < NEDGES) atomicAdd(&cntD[dst[e]], 1);
    return;
  }
  int bb = b - CNTB;
  if (bb < 64) {                       // W0 pack [128,128]
    int idx = bb * 256 + tid;
    int k = idx >> 7, c = idx & 127;
    Wp0[((size_t)((k >> 5) * 128 + c)) * 32 + (k & 31)] = f2bf(W0[idx]);
  } else if (bb < 128) {               // W1 pack [128,128]
    int idx = (bb - 64) * 256 + tid;
    int k = idx >> 7, c = idx & 127;
    Wp1[((size_t)((k >> 5) * 128 + c)) * 32 + (k & 31)] = f2bf(W1[idx]);
  } else if (bb < 160) {               // W2 pack [128,64]
    int idx = (bb - 128) * 256 + tid;
    int k = idx >> 6, c = idx & 63;
    Wp2[((size_t)((k >> 5) * 64 + c)) * 32 + (k & 31)] = f2bf(W2[idx]);
  } else {                             // lw1 fused pack [64,512] + biasAB + wh
    int idx = (bb - 160) * 256 + tid;
    int k = idx >> 9, c = idx & 511;
    float v = (c < 256) ? lw1[k * 256 + c] : lw1[(64 + k) * 256 + (c - 256)];
    WpE[((size_t)((k >> 5) * 512 + c)) * 32 + (k & 31)] = f2bf(v);
    if (idx < 512) biasAB[idx] = (idx < 256) ? lb1[idx] : 0.0f;
    if (idx < 128) {
      _Float16 lo = (_Float16)lw2[idx * 2];
      _Float16 hi = (_Float16)lw2[idx * 2 + 1];
      unsigned short ulo = __builtin_bit_cast(unsigned short, lo);
      unsigned short uhi = __builtin_bit_cast(unsigned short, hi);
      wh[idx] = (unsigned int)ulo | ((unsigned int)uhi << 16);
    }
  }
}

// ---------------- scanA (+ dis) ----------------
__global__ void scanA_kernel(const int* __restrict__ cntD, int* __restrict__ blockSum,
                             float* __restrict__ dis) {
  __shared__ int sh[256];
  int v = blockIdx.x * 256 + threadIdx.x;
  int c = (v < NNODES) ? cntD[v] : 0;
  if (v < NNODES) dis[v] = rsqrtf((float)(c + 1));  // deg = in-degree + self loop
  sh[threadIdx.x] = c;
  __syncthreads();
  for (int off = 128; off; off >>= 1) {
    if (threadIdx.x < off) sh[threadIdx.x] += sh[threadIdx.x + off];
    __syncthreads();
  }
  if (threadIdx.x == 0) blockSum[blockIdx.x] = sh[0];
}

__global__ void scanB_kernel(int* __restrict__ blockSum) {
  int lane = threadIdx.x;  // 0..63
  int carry = 0;
  for (int base = 0; base < NBLK; base += 64) {
    int i = base + lane;
    int c = (i < NBLK) ? blockSum[i] : 0;
    int pre = c;
#pragma unroll
    for (int off = 1; off < 64; off <<= 1) {
      int t = __shfl_up(pre, off);
      if (lane >= off) pre += t;
    }
    int tot = __shfl(pre, 63);
    if (i < NBLK) blockSum[i] = carry + pre - c;  // exclusive
    carry += tot;
  }
}

// ---------------- mgemm body (device fn) ----------------
template <int K, int HOUT, bool SCALE, bool BIAS, bool F32IN, bool F16OUT>
__device__ __forceinline__ void mgemm_body(int bid, const void* __restrict__ Xhi_v,
                                           const void* __restrict__ Xlo_v,
                                           const unsigned short* __restrict__ Wp,
                                           const float* __restrict__ dis,
                                           const float* __restrict__ bias,
                                           void* __restrict__ outv) {
  constexpr int KC = K / 32;
  const int tid = threadIdx.x;
  const int wave = tid >> 6;
  const int lane = tid & 63;
  const int lrow = lane & 15;
  const int lsub = lane >> 4;
  const int rowBase = bid * 64 + wave * 16;
  int arow = rowBase + lrow;
  if (arow > NNODES - 1) arow = NNODES - 1;
  bf16x8 ahi[KC], alo[KC];
  if constexpr (F32IN) {
    const float* xf = (const float*)Xhi_v;
#pragma unroll
    for (int kc = 0; kc < KC; ++kc) {
      float4 v0 = *(const float4*)&xf[(size_t)arow * K + kc * 32 + lsub * 8];
      float4 v1 = *(const float4*)&xf[(size_t)arow * K + kc * 32 + lsub * 8 + 4];
      float fv[8] = {v0.x, v0.y, v0.z, v0.w, v1.x, v1.y, v1.z, v1.w};
#pragma unroll
      for (int i = 0; i < 8; ++i) {
        unsigned short h = f2bf(fv[i]);
        ahi[kc][i] = (short)h;
        alo[kc][i] = (short)f2bf(fv[i] - bf2f(h));
      }
    }
  } else {
    const unsigned short* Xhi = (const unsigned short*)Xhi_v;
    const unsigned short* Xlo = (const unsigned short*)Xlo_v;
#pragma unroll
    for (int kc = 0; kc < KC; ++kc) {
      ahi[kc] = *(const bf16x8*)&Xhi[(size_t)arow * K + kc * 32 + lsub * 8];
      alo[kc] = *(const bf16x8*)&Xlo[(size_t)arow * K + kc * 32 + lsub * 8];
    }
  }
  int orow[4];
  float dis4[4];
#pragma unroll
  for (int i = 0; i < 4; ++i) {
    orow[i] = rowBase + lsub * 4 + i;
    int rc = orow[i] < NNODES ? orow[i] : NNODES - 1;
    dis4[i] = SCALE ? dis[rc] : 1.0f;
  }
  for (int ct = 0; ct < HOUT / 16; ++ct) {
    int c = ct * 16 + lrow;
    f32x4 acc = {0.f, 0.f, 0.f, 0.f};
#pragma unroll
    for (int kc = 0; kc < KC; ++kc) {
      bf16x8 b = *(const bf16x8*)&Wp[((size_t)(kc * HOUT + c)) * 32 + lsub * 8];
      acc = __builtin_amdgcn_mfma_f32_16x16x32_bf16(ahi[kc], b, acc, 0, 0, 0);
      acc = __builtin_amdgcn_mfma_f32_16x16x32_bf16(alo[kc], b, acc, 0, 0, 0);
    }
    float bb = BIAS ? bias[c] : 0.0f;
#pragma unroll
    for (int i = 0; i < 4; ++i) {
      if (orow[i] < NNODES) {
        float v = acc[i];
        if (SCALE) v *= dis4[i];
        if (BIAS) v += bb;
        if constexpr (F16OUT) {
          ((_Float16*)outv)[(size_t)orow[i] * HOUT + c] = (_Float16)v;
        } else {
          ((unsigned short*)outv)[(size_t)orow[i] * HOUT + c] = f2bf(v);
        }
      }
    }
  }
}

template <int K, int HOUT, bool SCALE, bool BIAS, bool F32IN, bool F16OUT>
__global__ __launch_bounds__(256)
void mgemm_kernel(const void* __restrict__ Xhi_v, const void* __restrict__ Xlo_v,
                  const unsigned short* __restrict__ Wp, const float* __restrict__ dis,
                  const float* __restrict__ bias, void* __restrict__ outv) {
  mgemm_body<K, HOUT, SCALE, BIAS, F32IN, F16OUT>(blockIdx.x, Xhi_v, Xlo_v, Wp, dis, bias, outv);
}

// ---------------- K4: mgemm L0 ∥ scanC ----------------
__global__ __launch_bounds__(256)
void mg0_scanC_kernel(const float* __restrict__ x, const unsigned short* __restrict__ Wp0,
                      const float* __restrict__ dis, unsigned short* __restrict__ P16,
                      const int* __restrict__ cntD, const int* __restrict__ blockSum,
                      int* __restrict__ startD, int* __restrict__ curD) {
  if (blockIdx.x < GB0) {
    mgemm_body<128, 128, true, false, true, false>(blockIdx.x, x, nullptr, Wp0, dis, nullptr, P16);
    return;
  }
  // scanC
  __shared__ int sh[256];
  int bid = blockIdx.x - GB0;
  int tid = threadIdx.x;
  int v = bid * 256 + tid;
  int c = (v < NNODES) ? cntD[v] : 0;
  sh[tid] = c;
  __syncthreads();
  for (int off = 1; off < 256; off <<= 1) {
    int t = (tid >= off) ? sh[tid - off] : 0;
    __syncthreads();
    sh[tid] += t;
    __syncthreads();
  }
  if (v < NNODES) {
    int s = blockSum[bid] + sh[tid] - c;  // exclusive prefix
    startD[v] = s;
    curD[v] = s;
  }
}

// ---------------- fill (dst-range sliced for write locality) ----------------
__global__ void fill_kernel(const int* __restrict__ src, const int* __restrict__ dst,
                            int* __restrict__ curD, int2* __restrict__ csrPair) {
  int slice = blockIdx.x & (NSLICE - 1);
  int e = (blockIdx.x >> 3) * 256 + threadIdx.x;
  if (e >= NEDGES) return;
  int d = dst[e];
  int lo = slice * SLICEW;
  if (d < lo || d >= lo + SLICEW) return;
  int s = src[e];
  int pd = atomicAdd(&curD[d], 1);
  csrPair[pd] = make_int2(s, e);
}

// ---------------- aggregation: one wave per node, bf16 messages -> split bf16 z ----------------
template <int HOUT>
__global__ __launch_bounds__(256)
void agg_kernel(const unsigned short* __restrict__ hws, const int2* __restrict__ csrPair,
                const int* __restrict__ startA, const int* __restrict__ cnt,
                const float* __restrict__ dis, const float* __restrict__ bias,
                unsigned short* __restrict__ outHi, unsigned short* __restrict__ outLo) {
  int gid = blockIdx.x * 256 + threadIdx.x;
  int v = gid >> 6;
  int lane = gid & 63;
  constexpr int PER = HOUT / 64;
  float acc0 = 0.0f, acc1 = 0.0f;
  if constexpr (PER == 2) {
    unsigned int o = *(const unsigned int*)&hws[(size_t)v * HOUT + lane * 2];
    acc0 = __uint_as_float(o << 16);
    acc1 = __uint_as_float(o & 0xffff0000u);
  } else {
    acc0 = bf2f(hws[(size_t)v * HOUT + lane]);
  }
  int s0 = startA[v], c = cnt[v];
  for (int base = 0; base < c; base += 64) {
    int rem = c - base;
    int m = rem < 64 ? rem : 64;
    int idx = 0;
    if (lane < m) idx = csrPair[s0 + base + lane].x;
    int j = 0;
    for (; j + 8 <= m; j += 8) {   // 8-deep gather pipeline
      int u0 = __shfl(idx, j);
      int u1 = __shfl(idx, j + 1);
      int u2 = __shfl(idx, j + 2);
      int u3 = __shfl(idx, j + 3);
      int u4 = __shfl(idx, j + 4);
      int u5 = __shfl(idx, j + 5);
      int u6 = __shfl(idx, j + 6);
      int u7 = __shfl(idx, j + 7);
      if constexpr (PER == 2) {
        unsigned int r0 = *(const unsigned int*)&hws[(size_t)u0 * HOUT + lane * 2];
        unsigned int r1 = *(const unsigned int*)&hws[(size_t)u1 * HOUT + lane * 2];
        unsigned int r2 = *(const unsigned int*)&hws[(size_t)u2 * HOUT + lane * 2];
        unsigned int r3 = *(const unsigned int*)&hws[(size_t)u3 * HOUT + lane * 2];
        unsigned int r4 = *(const unsigned int*)&hws[(size_t)u4 * HOUT + lane * 2];
        unsigned int r5 = *(const unsigned int*)&hws[(size_t)u5 * HOUT + lane * 2];
        unsigned int r6 = *(const unsigned int*)&hws[(size_t)u6 * HOUT + lane * 2];
        unsigned int r7 = *(const unsigned int*)&hws[(size_t)u7 * HOUT + lane * 2];
        acc0 += (__uint_as_float(r0 << 16) + __uint_as_float(r1 << 16)) +
                (__uint_as_float(r2 << 16) + __uint_as_float(r3 << 16)) +
                (__uint_as_float(r4 << 16) + __uint_as_float(r5 << 16)) +
                (__uint_as_float(r6 << 16) + __uint_as_float(r7 << 16));
        acc1 += (__uint_as_float(r0 & 0xffff0000u) + __uint_as_float(r1 & 0xffff0000u)) +
                (__uint_as_float(r2 & 0xffff0000u) + __uint_as_float(r3 & 0xffff0000u)) +
                (__uint_as_float(r4 & 0xffff0000u) + __uint_as_float(r5 & 0xffff0000u)) +
                (__uint_as_float(r6 & 0xffff0000u) + __uint_as_float(r7 & 0xffff0000u));
      } else {
        float r0 = bf2f(hws[(size_t)u0 * HOUT + lane]);
        float r1 = bf2f(hws[(size_t)u1 * HOUT + lane]);
        float r2 = bf2f(hws[(size_t)u2 * HOUT + lane]);
        float r3 = bf2f(hws[(size_t)u3 * HOUT + lane]);
        float r4 = bf2f(hws[(size_t)u4 * HOUT + lane]);
        float r5 = bf2f(hws[(size_t)u5 * HOUT + lane]);
        float r6 = bf2f(hws[(size_t)u6 * HOUT + lane]);
        float r7 = bf2f(hws[(size_t)u7 * HOUT + lane]);
        acc0 += ((r0 + r1) + (r2 + r3)) + ((r4 + r5) + (r6 + r7));
      }
    }
    for (; j + 4 <= m; j += 4) {
      int u0 = __shfl(idx, j);
      int u1 = __shfl(idx, j + 1);
      int u2 = __shfl(idx, j + 2);
      int u3 = __shfl(idx, j + 3);
      if constexpr (PER == 2) {
        unsigned int r0 = *(const unsigned int*)&hws[(size_t)u0 * HOUT + lane * 2];
        unsigned int r1 = *(const unsigned int*)&hws[(size_t)u1 * HOUT + lane * 2];
        unsigned int r2 = *(const unsigned int*)&hws[(size_t)u2 * HOUT + lane * 2];
        unsigned int r3 = *(const unsigned int*)&hws[(size_t)u3 * HOUT + lane * 2];
        acc0 += __uint_as_float(r0 << 16) + __uint_as_float(r1 << 16) +
                __uint_as_float(r2 << 16) + __uint_as_float(r3 << 16);
        acc1 += __uint_as_float(r0 & 0xffff0000u) + __uint_as_float(r1 & 0xffff0000u) +
                __uint_as_float(r2 & 0xffff0000u) + __uint_as_float(r3 & 0xffff0000u);
      } else {
        float r0 = bf2f(hws[(size_t)u0 * HOUT + lane]);
        float r1 = bf2f(hws[(size_t)u1 * HOUT + lane]);
        float r2 = bf2f(hws[(size_t)u2 * HOUT + lane]);
        float r3 = bf2f(hws[(size_t)u3 * HOUT + lane]);
        acc0 += (r0 + r1) + (r2 + r3);
      }
    }
    for (; j < m; ++j) {
      int u = __shfl(idx, j);
      if constexpr (PER == 2) {
        unsigned int r = *(const unsigned int*)&hws[(size_t)u * HOUT + lane * 2];
        acc0 += __uint_as_float(r << 16);
        acc1 += __uint_as_float(r & 0xffff0000u);
      } else {
        acc0 += bf2f(hws[(size_t)u * HOUT + lane]);
      }
    }
  }
  float d = dis[v];
  if constexpr (PER == 2) {
    float o0 = fmaf(d, acc0, bias[lane * 2]);
    float o1 = fmaf(d, acc1, bias[lane * 2 + 1]);
    o0 = o0 > 0.0f ? o0 : 0.0f;
    o1 = o1 > 0.0f ? o1 : 0.0f;
    ushort2 h, l;
    h.x = f2bf(o0); l.x = f2bf(o0 - bf2f(h.x));
    h.y = f2bf(o1); l.y = f2bf(o1 - bf2f(h.y));
    *(ushort2*)&outHi[(size_t)v * HOUT + lane * 2] = h;
    *(ushort2*)&outLo[(size_t)v * HOUT + lane * 2] = l;
  } else {
    float o0 = fmaf(d, acc0, bias[lane]);
    o0 = o0 > 0.0f ? o0 : 0.0f;
    unsigned short h = f2bf(o0);
    outHi[(size_t)v * HOUT + lane] = h;
    outLo[(size_t)v * HOUT + lane] = f2bf(o0 - bf2f(h));
  }
}

// ---------------- edge classifier: one wave per DST node, fp16 packed, fused sigmoid ----------------
__global__ __launch_bounds__(256)
void edge_kernel(const unsigned int* __restrict__ AB32,
                 const int2* __restrict__ csrPair,
                 const int* __restrict__ startD, const int* __restrict__ cntD,
                 const unsigned int* __restrict__ wh, const float* __restrict__ lb2,
                 float* __restrict__ out) {
  int gid = blockIdx.x * 256 + threadIdx.x;
  int v = gid >> 6;
  int lane = gid & 63;
  int sub = lane & 15;
  unsigned int zero = 0u;
  unsigned int bu[8], wu[8];
  {
    const unsigned int* Brow = AB32 + (size_t)v * 256 + 128 + sub * 8;
    uint4 b0 = *(const uint4*)Brow;
    uint4 b1 = *(const uint4*)(Brow + 4);
    bu[0] = b0.x; bu[1] = b0.y; bu[2] = b0.z; bu[3] = b0.w;
    bu[4] = b1.x; bu[5] = b1.y; bu[6] = b1.z; bu[7] = b1.w;
    const unsigned int* W = wh + sub * 8;
    uint4 w0 = *(const uint4*)W;
    uint4 w1 = *(const uint4*)(W + 4);
    wu[0] = w0.x; wu[1] = w0.y; wu[2] = w0.z; wu[3] = w0.w;
    wu[4] = w1.x; wu[5] = w1.y; wu[6] = w1.z; wu[7] = w1.w;
  }
  float lb = lb2[0];

  int s0 = startD[v], c = cntD[v];
  for (int base = 0; base < c; base += 64) {
    int rem = c - base;
    int m = rem < 64 ? rem : 64;
    int sj = 0, ej = 0;
    if (lane < m) {
      int2 p = csrPair[s0 + base + lane];
      sj = p.x; ej = p.y;
    }
    int g = lane >> 4;
    for (int j = 0; j < m; j += 8) {
      int ls0 = j + g, ls1 = j + 4 + g;
      int l0 = ls0 < m ? ls0 : m - 1;
      int l1 = ls1 < m ? ls1 : m - 1;
      int sA = __shfl(sj, l0);
      int eA = __shfl(ej, l0);
      int sB = __shfl(sj, l1);
      int eB = __shfl(ej, l1);
      const unsigned int* ArowA = AB32 + (size_t)(unsigned)sA * 256 + sub * 8;
      const unsigned int* ArowB = AB32 + (size_t)(unsigned)sB * 256 + sub * 8;
      uint4 a00 = *(const uint4*)ArowA;
      uint4 a01 = *(const uint4*)(ArowA + 4);
      uint4 a10 = *(const uint4*)ArowB;
      uint4 a11 = *(const uint4*)(ArowB + 4);
      unsigned int au0[8] = {a00.x, a00.y, a00.z, a00.w, a01.x, a01.y, a01.z, a01.w};
      unsigned int au1[8] = {a10.x, a10.y, a10.z, a10.w, a11.x, a11.y, a11.z, a11.w};
      float acc0 = 0.f, acc1 = 0.f;
#pragma unroll
      for (int i = 0; i < 8; ++i) {
        unsigned int h0 = pk_max0_f16(pk_add_f16(au0[i], bu[i]), zero);
        acc0 = dot2_f16(h0, wu[i], acc0);
        unsigned int h1 = pk_max0_f16(pk_add_f16(au1[i], bu[i]), zero);
        acc1 = dot2_f16(h1, wu[i], acc1);
      }
      acc0 += __shfl_xor(acc0, 1);
      acc0 += __shfl_xor(acc0, 2);
      acc0 += __shfl_xor(acc0, 4);
      acc0 += __shfl_xor(acc0, 8);
      acc1 += __shfl_xor(acc1, 1);
      acc1 += __shfl_xor(acc1, 2);
      acc1 += __shfl_xor(acc1, 4);
      acc1 += __shfl_xor(acc1, 8);
      if (ls0 < m && sub == 0) out[eA] = 1.0f / (1.0f + expf(-(acc0 + lb)));
      if (ls1 < m && sub == 0) out[eB] = 1.0f / (1.0f + expf(-(acc1 + lb)));
    }
  }
}

extern "C" void kernel_launch(void* const* d_in, const int* in_sizes, int n_in,
                              void* d_out, int out_size, void* d_ws, size_t ws_size,
                              hipStream_t stream) {
  const float* x   = (const float*)d_in[0];
  const int*   ei  = (const int*)d_in[1];
  const float* W0  = (const float*)d_in[2];
  const float* b0  = (const float*)d_in[3];
  const float* W1  = (const float*)d_in[4];
  const float* b1  = (const float*)d_in[5];
  const float* W2  = (const float*)d_in[6];
  const float* b2  = (const float*)d_in[7];
  const float* lw1 = (const float*)d_in[8];
  const float* lb1 = (const float*)d_in[9];
  const float* lw2 = (const float*)d_in[10];
  const float* lb2 = (const float*)d_in[11];
  float* out = (float*)d_out;
  const int* src = ei;
  const int* dst = ei + NEDGES;

  char* ws = (char*)d_ws;
  size_t off = 0;
  auto alloc = [&](size_t bytes) -> void* {
    void* p = ws + off;
    off += (bytes + 255) & ~(size_t)255;
    return p;
  };
  int*   cntD   = (int*)alloc((size_t)NNODES * 4);
  int*   startD = (int*)alloc((size_t)NNODES * 4);
  int*   curD   = (int*)alloc((size_t)NNODES * 4);
  float* dis    = (float*)alloc((size_t)NNODES * 4);
  int*   blockSum = (int*)alloc((size_t)NBLK * 4);
  int2*  csrPair= (int2*)alloc((size_t)NEDGES * 8);
  unsigned short* P16  = (unsigned short*)alloc((size_t)NNODES * 128 * 2);
  unsigned short* XQhi = (unsigned short*)alloc((size_t)NNODES * 128 * 2);
  unsigned short* XQlo = (unsigned short*)alloc((size_t)NNODES * 128 * 2);
  void*           AB   = alloc((size_t)NNODES * 512 * 2);   // fp16 A|B tables
  unsigned short* Wp0  = (unsigned short*)alloc((size_t)128 * 128 * 2);
  unsigned short* Wp1  = (unsigned short*)alloc((size_t)128 * 128 * 2);
  unsigned short* Wp2  = (unsigned short*)alloc((size_t)128 * 64 * 2);
  unsigned short* WpE  = (unsigned short*)alloc((size_t)64 * 512 * 2);
  float* biasAB = (float*)alloc(512 * 4);
  unsigned int* wh = (unsigned int*)alloc(128 * 4);

  const int EB8 = NSLICE * CNTB;       // sliced fill grid
  const int AB_ = (NNODES * 64) / 256; // one wave per node

  hipMemsetAsync(cntD, 0, (size_t)NNODES * 4, stream);
  // K1: count ∥ all weight packs
  k1_kernel<<<CNTB + 288, 256, 0, stream>>>(dst, cntD, W0, W1, W2, lw1, lb1, lw2,
                                            Wp0, Wp1, Wp2, WpE, biasAB, wh);
  scanA_kernel<<<NBLK, 256, 0, stream>>>(cntD, blockSum, dis);
  scanB_kernel<<<1, 64, 0, stream>>>(blockSum);
  // K4: mgemm layer-0 ∥ scanC (independent: mgemm needs dis/x/Wp0, scanC needs blockSum)
  mg0_scanC_kernel<<<GB0 + NBLK, 256, 0, stream>>>(x, Wp0, dis, P16, cntD, blockSum, startD, curD);
  fill_kernel<<<EB8, 256, 0, stream>>>(src, dst, curD, csrPair);

  agg_kernel<128><<<AB_, 256, 0, stream>>>(P16, csrPair, startD, cntD, dis, b0, XQhi, XQlo);
  mgemm_kernel<128, 128, true, false, false, false><<<GB0, 256, 0, stream>>>(XQhi, XQlo, Wp1, dis, nullptr, P16);
  agg_kernel<128><<<AB_, 256, 0, stream>>>(P16, csrPair, startD, cntD, dis, b1, XQhi, XQlo);
  mgemm_kernel<128, 64, true, false, false, false><<<GB0, 256, 0, stream>>>(XQhi, XQlo, Wp2, dis, nullptr, P16);
  agg_kernel<64><<<AB_, 256, 0, stream>>>(P16, csrPair, startD, cntD, dis, b2, XQhi, XQlo);

  mgemm_kernel<64, 512, false, true, false, true><<<GB0, 256, 0, stream>>>(XQhi, XQlo, WpE, nullptr, biasAB, AB);

  edge_kernel<<<AB_, 256, 0, stream>>>((const unsigned int*)AB, csrPair, startD, cntD, wh, lb2, out);
}